// Round 3
// baseline (411.395 us; speedup 1.0000x reference)
//
#include <hip/hip_runtime.h>
#include <stdint.h>

// ---------------- problem dims ----------------
#define B_DIM 64
#define P_DIM 225
#define K_DIM 16
#define D_DIM 640
#define M_REAL (B_DIM * P_DIM)   // 14400 query rows
#define N_REAL (K_DIM * P_DIM)   // 3600 reference rows

// ---------------- GEMM tiling (256x256, 8-phase schedule) ----------------
#define BM 256
#define BN 256
#define MTILES 57                // ceil(14400/256) -> Mpad 14592
#define NTILES 15                // ceil(3600/256)  -> Npad 3840
#define MPAD (MTILES * BM)
#define NPAD (NTILES * BN)
#define MC 8                     // ceil(MTILES/8) per-XCD bm groups

typedef float f32x4 __attribute__((ext_vector_type(4)));
typedef int   i32x4 __attribute__((ext_vector_type(4)));
typedef int   i32x8 __attribute__((ext_vector_type(8)));

// ---------------- helpers ----------------
// float -> OCP e4m3 byte (v_cvt_pk_fp8_f32)
__device__ __forceinline__ unsigned char f2fp8(float f) {
  int r = __builtin_amdgcn_cvt_pk_fp8_f32(f, f, 0, false);
  return (unsigned char)(r & 0xFF);
}

// monotone float -> uint key (order-preserving), for atomicMax on floats
__device__ __forceinline__ unsigned f2key(float f) {
  union { float f; unsigned u; } v; v.f = f;
  unsigned u = v.u;
  return (u & 0x80000000u) ? ~u : (u | 0x80000000u);
}
__device__ __forceinline__ float key2f(unsigned k) {
  unsigned b = (k & 0x80000000u) ? (k ^ 0x80000000u) : ~k;
  union { unsigned u; float f; } v; v.u = b;
  return v.f;
}

__device__ __forceinline__ void gl_lds16(const void* g, void* l) {
  __builtin_amdgcn_global_load_lds(
      (const __attribute__((address_space(1))) void*)g,
      (__attribute__((address_space(3))) void*)l,
      16, 0, 0);
}

__device__ __forceinline__ float sigmoidf(float x) {
  return 1.f / (1.f + expf(-x));
}

// =====================================================================
// Kernel A: staging (fp8 e4m3 outputs) — pad sizes track MPAD/NPAD.
// =====================================================================
#define QBLKS (MPAD / 4)
#define RBLKS (NPAD / 4)
#define ABLKS 16
__global__ __launch_bounds__(256) void stage_all_kernel(
    const float* __restrict__ q, const float* __restrict__ r,
    const float* __restrict__ r_img, const float* __restrict__ aw1,
    unsigned char* __restrict__ qb, unsigned char* __restrict__ rb,
    float* __restrict__ qinv, unsigned* __restrict__ rowmax,
    float* __restrict__ h1) {
  const int blk = blockIdx.x;
  const int tid = threadIdx.x;

  if (blk < ABLKS) {
    __shared__ float rk_s[D_DIM];
    const int k = blk;
    for (int i = tid; i < D_DIM; i += 256) rk_s[i] = r_img[k * D_DIM + i];
    __syncthreads();
    if (tid < 160) {
      const int j = tid;
      float a = 0.f;
#pragma unroll 8
      for (int d = 0; d < D_DIM; d++) a += rk_s[d] * aw1[d * 160 + j];
      h1[k * 160 + j] = fmaxf(a, 0.f);
    }
    return;
  }

  if (blk < ABLKS + QBLKS) {
    int row = (blk - ABLKS) * 4 + (tid >> 6);
    int lane = tid & 63;
    if (lane == 0) rowmax[row] = 0u;
    unsigned char* dst = qb + (long)row * D_DIM;
    if (row >= M_REAL) {
#pragma unroll
      for (int i = 0; i < 10; i++) dst[i * 64 + lane] = 0;
      return;
    }
    const float* src = q + (long)row * D_DIM;
    float v[10];
    float ss = 0.f;
#pragma unroll
    for (int i = 0; i < 10; i++) { v[i] = src[i * 64 + lane]; ss += v[i] * v[i]; }
#pragma unroll
    for (int off = 32; off > 0; off >>= 1) ss += __shfl_xor(ss, off);
    float inv = 1.f / (sqrtf(ss) + 1e-6f);
    if (lane == 0) qinv[row] = inv * (1.f / 16.f);  // fold r-scale
#pragma unroll
    for (int i = 0; i < 10; i++) dst[i * 64 + lane] = f2fp8(v[i]);
    return;
  }

  {
    int row = (blk - ABLKS - QBLKS) * 4 + (tid >> 6);
    int lane = tid & 63;
    unsigned char* dst = rb + (long)row * D_DIM;
    if (row >= N_REAL) {
#pragma unroll
      for (int i = 0; i < 10; i++) dst[i * 64 + lane] = 0;
      return;
    }
    const float* src = r + (long)row * D_DIM;
    float v[10];
    float ss = 0.f;
#pragma unroll
    for (int i = 0; i < 10; i++) { v[i] = src[i * 64 + lane]; ss += v[i] * v[i]; }
#pragma unroll
    for (int off = 32; off > 0; off >>= 1) ss += __shfl_xor(ss, off);
    float sc = 16.f / (sqrtf(ss) + 1e-6f);   // normalize, x16 into e4m3 normals
#pragma unroll
    for (int i = 0; i < 10; i++) dst[i * 64 + lane] = f2fp8(v[i] * sc);
  }
}

// =====================================================================
// Kernel B: 256x256 MX-fp8 MFMA GEMM + row-max, 8-phase schedule
//   (T3+T4 port of the proven 256sq template; 512 thr = 8 waves 2x4).
//   Per K-tile (128 B): 4 phases; each = {ds_read 2 A-frags (+B frags
//   at p0) || issue 2 gl_lds of next tile's quarter} -> s_barrier ->
//   setprio(1) 8 MFMA setprio(0) -> s_barrier.  vmcnt(0) ONLY at the
//   K-tile boundary (one phase of slack), never inside phases.
//   LDS: 2 x (A 32KB + B 32KB) = 128 KB.  XOR swizzle as before
//   (chunk ^= row&7; staged via pre-swizzled GLOBAL source, rule #21).
// =====================================================================
__global__ __launch_bounds__(512, 2) void sim_max_kernel(
    const unsigned char* __restrict__ Qb,
    const unsigned char* __restrict__ Rb,
    unsigned* __restrict__ rowmax) {
  __shared__ __attribute__((aligned(16))) unsigned char As[2][BM * 128];  // 2x32 KB
  __shared__ __attribute__((aligned(16))) unsigned char Bs[2][BN * 128];  // 2x32 KB

  const int xcd = blockIdx.x & 7;
  const int idx = blockIdx.x >> 3;
  const int bm = xcd + 8 * (idx % MC);
  const int bn = idx / MC;
  if (bm >= MTILES) return;

  const int tid = threadIdx.x;
  const int lane = tid & 63;
  const int wave = tid >> 6;
  const int wr = wave >> 2, wc = wave & 3;   // 2 x 4 wave grid
  const int q = lane >> 4, m0 = lane & 15;   // k-chunk (32B) / frag row

  // ---- staging geometry: 512 threads cover 64 rows x 8 chunks (8 KB) ----
  const int sRow = tid >> 3;                 // 0..63
  const int sp = tid & 7;                    // phys 16B chunk
  const int sSrcC = (sp ^ (sRow & 7)) << 4;  // pre-swizzled source byte
  const int sLds = tid * 16;                 // linear LDS dest within quarter

  // ---- frag read LDS byte offsets (row&7 == m0&7 for all mi/ni) ----
  const int r7 = m0 & 15 & 7;
  const int cLo = (((q << 1) | 0) ^ r7) << 4;
  const int cHi = (((q << 1) | 1) ^ r7) << 4;

  const int aBase = bm * BM;
  const int bBase = bn * BN;

  f32x4 zero = {0.f, 0.f, 0.f, 0.f};
  f32x4 acc[8][4];
#pragma unroll
  for (int i = 0; i < 8; i++)
#pragma unroll
    for (int j = 0; j < 4; j++) acc[i][j] = zero;

  union frag_u { i32x8 v; i32x4 h[2]; };

  // stage quarter P (A rows P*64..+63 and B same) of K-tile KT into buffer BUF
#define STAGE_Q(KT, P, BUF)                                                   \
  {                                                                           \
    const int row_ = (P) * 64 + sRow;                                         \
    gl_lds16(Qb + (size_t)(aBase + row_) * D_DIM + (KT) * 128 + sSrcC,        \
             &As[BUF][(P) * 8192 + sLds]);                                    \
    gl_lds16(Rb + (size_t)(bBase + row_) * D_DIM + (KT) * 128 + sSrcC,        \
             &Bs[BUF][(P) * 8192 + sLds]);                                    \
  }

  // prologue: stage full tile 0 into buf 0, gate
  STAGE_Q(0, 0, 0); STAGE_Q(0, 1, 0); STAGE_Q(0, 2, 0); STAGE_Q(0, 3, 0);
  asm volatile("s_waitcnt vmcnt(0)" ::: "memory");
  __builtin_amdgcn_s_barrier();

  frag_u bf[4];

#pragma unroll
  for (int kt = 0; kt < 5; kt++) {
    const int cur = kt & 1;
#pragma unroll
    for (int p = 0; p < 4; p++) {
      // ---- ds-region: frag reads + next-tile quarter prefetch ----
      if (p == 0) {
#pragma unroll
        for (int ni = 0; ni < 4; ni++) {
          const int rb_ = (wc * 64 + ni * 16 + m0) * 128;
          bf[ni].h[0] = *(const i32x4*)&Bs[cur][rb_ + cLo];
          bf[ni].h[1] = *(const i32x4*)&Bs[cur][rb_ + cHi];
        }
      }
      frag_u af0, af1;
      {
        const int r0 = (wr * 128 + (2 * p + 0) * 16 + m0) * 128;
        const int r1 = (wr * 128 + (2 * p + 1) * 16 + m0) * 128;
        af0.h[0] = *(const i32x4*)&As[cur][r0 + cLo];
        af0.h[1] = *(const i32x4*)&As[cur][r0 + cHi];
        af1.h[0] = *(const i32x4*)&As[cur][r1 + cLo];
        af1.h[1] = *(const i32x4*)&As[cur][r1 + cHi];
      }
      if (kt < 4) STAGE_Q(kt + 1, p, cur ^ 1);

      __builtin_amdgcn_s_barrier();   // pre-MFMA barrier (phase split)

      __builtin_amdgcn_s_setprio(1);
#pragma unroll
      for (int ni = 0; ni < 4; ni++)
        acc[2 * p + 0][ni] = __builtin_amdgcn_mfma_scale_f32_16x16x128_f8f6f4(
            af0.v, bf[ni].v, acc[2 * p + 0][ni],
            0, 0, 0, 0x7F7F7F7Fu, 0, 0x7F7F7F7Fu);
#pragma unroll
      for (int ni = 0; ni < 4; ni++)
        acc[2 * p + 1][ni] = __builtin_amdgcn_mfma_scale_f32_16x16x128_f8f6f4(
            af1.v, bf[ni].v, acc[2 * p + 1][ni],
            0, 0, 0, 0x7F7F7F7Fu, 0, 0x7F7F7F7Fu);
      __builtin_amdgcn_s_setprio(0);

      // K-tile boundary: drain the tile we just finished prefetching
      // (issued across the 4 phases -> ~1 phase of slack on the last one)
      if (p == 3 && kt < 4) asm volatile("s_waitcnt vmcnt(0)" ::: "memory");
      if (!(p == 3 && kt == 4)) __builtin_amdgcn_s_barrier();  // post-MFMA
    }
  }
#undef STAGE_Q

  // epilogue: per-row max over this block's 256 columns, then global atomicMax
  // (C/D layout for 16x16 shapes: col = lane&15, row = (lane>>4)*4 + reg)
  const int colBase = bn * BN + wc * 64;
#pragma unroll
  for (int mi = 0; mi < 8; mi++) {
    float rmax[4] = {-3.0e38f, -3.0e38f, -3.0e38f, -3.0e38f};
#pragma unroll
    for (int ni = 0; ni < 4; ni++) {
      bool valid = (colBase + ni * 16 + m0) < N_REAL;
#pragma unroll
      for (int r = 0; r < 4; r++) {
        float v = valid ? acc[mi][ni][r] : -3.0e38f;
        rmax[r] = fmaxf(rmax[r], v);
      }
    }
#pragma unroll
    for (int r = 0; r < 4; r++) {
      float v = rmax[r];
      v = fmaxf(v, __shfl_xor(v, 1));
      v = fmaxf(v, __shfl_xor(v, 2));
      v = fmaxf(v, __shfl_xor(v, 4));
      v = fmaxf(v, __shfl_xor(v, 8));
      rmax[r] = v;
    }
    if (m0 == 0) {
      int row = bm * BM + wr * 128 + mi * 16 + q * 4;
#pragma unroll
      for (int r = 0; r < 4; r++)
        atomicMax(&rowmax[row + r], f2key(rmax[r]));
    }
  }
}

// =====================================================================
// Kernel T1: tail part 1 (unchanged).
// =====================================================================
__global__ __launch_bounds__(256) void tail1_kernel(
    const float* __restrict__ h1, const float* __restrict__ aw2,
    const unsigned* __restrict__ rowmax, const float* __restrict__ qinv,
    const float* __restrict__ hw1, const float* __restrict__ hb1,
    const float* __restrict__ hg2, const float* __restrict__ hbe2,
    float* __restrict__ favg, float* __restrict__ h1m,
    float* __restrict__ amean) {
  __shared__ __attribute__((aligned(16))) float S[12800];  // 51.2 KB
  const int blk = blockIdx.x;
  const int tid = threadIdx.x;
  const int wave = tid >> 6, lane = tid & 63;

  if (blk < 10) {
    const int d0 = blk * 64;
#pragma unroll
    for (int i = 0; i < 10; i++) S[i * 256 + tid] = h1[i * 256 + tid];
#pragma unroll
    for (int c = 0; c < 10; c++) {
      int e = c * 256 + tid;
      int row = e >> 4, col16 = e & 15;
      gl_lds16((const char*)aw2 + (size_t)row * D_DIM * 4 + d0 * 4 + col16 * 16,
               (char*)&S[2560] + e * 16);
    }
    __syncthreads();

    const int d = tid & 63, kg = tid >> 6;
    float a0 = 0.f, a1 = 0.f, a2 = 0.f, a3 = 0.f;
#pragma unroll 8
    for (int j = 0; j < 160; j++) {
      float w = S[2560 + j * 64 + d];
      a0 += S[(kg * 4 + 0) * 160 + j] * w;
      a1 += S[(kg * 4 + 1) * 160 + j] * w;
      a2 += S[(kg * 4 + 2) * 160 + j] * w;
      a3 += S[(kg * 4 + 3) * 160 + j] * w;
    }
    float p = fmaxf(a0, 0.f) + fmaxf(a1, 0.f) + fmaxf(a2, 0.f) + fmaxf(a3, 0.f);
    __syncthreads();
    S[kg * 64 + d] = p;
    __syncthreads();
    if (kg == 0)
      favg[d0 + d] = (S[d] + S[64 + d] + S[128 + d] + S[192 + d]) * (1.f / 16.f);
    return;
  }

  const int bO = (blk - 10) * 8;
  for (int e = tid; e < 8 * P_DIM; e += 256) {
    int row = bO * P_DIM + e;
    float mx = key2f(rowmax[row]);
    S[e] = 0.5f * (1.f - mx * qinv[row]);
  }
  __syncthreads();

#pragma unroll
  for (int i = 0; i < 2; i++) {
    int b = wave * 2 + i;
    float s = S[b * P_DIM + lane];
    s += S[b * P_DIM + lane + 64];
    s += S[b * P_DIM + lane + 128];
    if (lane < 33) s += S[b * P_DIM + lane + 192];
#pragma unroll
    for (int off = 32; off > 0; off >>= 1) s += __shfl_xor(s, off);
    if (lane == 0) amean[bO + b] = s * (1.f / 225.f);
  }

  const int j = tid & 127, bh = tid >> 7;
  float acc[4];
#pragma unroll
  for (int bb = 0; bb < 4; bb++) acc[bb] = hb1[j];

  for (int t = 0; t < 7; t++) {
    int p0 = t * 32;
#pragma unroll
    for (int c = 0; c < 4; c++) {
      int e = c * 256 + tid;
      int row = e >> 5, col16 = e & 31;
      gl_lds16((const char*)hw1 + (size_t)(p0 + row) * 128 * 4 + col16 * 16,
               (char*)&S[1800] + e * 16);
    }
    __syncthreads();
#pragma unroll 4
    for (int pr = 0; pr < 32; pr++) {
      float w = S[1800 + pr * 128 + j];
#pragma unroll
      for (int bb = 0; bb < 4; bb++)
        acc[bb] += S[(bh * 4 + bb) * P_DIM + p0 + pr] * w;
    }
    __syncthreads();
  }
  {
    float w = hw1[224 * 128 + j];
#pragma unroll
    for (int bb = 0; bb < 4; bb++)
      acc[bb] += S[(bh * 4 + bb) * P_DIM + 224] * w;
  }
#pragma unroll
  for (int bb = 0; bb < 4; bb++) {
    float h = fmaxf(acc[bb], 0.f) * hg2[j] + hbe2[j];
    h1m[(bO + bh * 4 + bb) * 128 + j] = h;
  }
}

// =====================================================================
// Kernel T2: tail part 2 (unchanged).
// =====================================================================
__global__ __launch_bounds__(256) void tail2_kernel(
    const float* __restrict__ q_img, const float* __restrict__ favg,
    const float* __restrict__ h1m, const float* __restrict__ amean,
    const float* __restrict__ hw2, const float* __restrict__ hb2,
    const float* __restrict__ hg3, const float* __restrict__ hbe3,
    const float* __restrict__ hw3, const float* __restrict__ hb3,
    const float* __restrict__ rw1, const float* __restrict__ rb1,
    const float* __restrict__ rg2, const float* __restrict__ rbe2,
    const float* __restrict__ rw2, const float* __restrict__ rb2,
    const float* __restrict__ rg3, const float* __restrict__ rbe3,
    const float* __restrict__ rw3, const float* __restrict__ rb3,
    float* __restrict__ out) {
  __shared__ __attribute__((aligned(16))) float S[14336];  // 57.3 KB
  const int tid = threadIdx.x;
  const int wave = tid >> 6, lane = tid & 63;
  const int bO = blockIdx.x * 8;

#pragma unroll
  for (int i = 0; i < 20; i++) {
    int e = i * 256 + tid;
    int d = e % D_DIM;
    S[e] = q_img[bO * D_DIM + e] - favg[d];
  }

#pragma unroll
  for (int c = 0; c < 4; c++) {
    int e = c * 256 + tid;
    int row = e >> 5, col16 = e & 31;
    gl_lds16((const char*)rw1 + (size_t)row * 128 * 4 + col16 * 16,
             (char*)&S[5120] + e * 16);
  }
  __syncthreads();

  const int j = tid & 127, bh = tid >> 7;
  float acc[4];
#pragma unroll
  for (int bb = 0; bb < 4; bb++) acc[bb] = rb1[j];

  for (int t = 0; t < 20; t++) {
    int bufC = 5120 + (t & 1) * 4096;
    int bufN = 5120 + ((t + 1) & 1) * 4096;
    if (t < 19) {
      int d0n = (t + 1) * 32;
#pragma unroll
      for (int c = 0; c < 4; c++) {
        int e = c * 256 + tid;
        int row = e >> 5, col16 = e & 31;
        gl_lds16((const char*)rw1 + (size_t)(d0n + row) * 128 * 4 + col16 * 16,
                 (char*)&S[bufN] + e * 16);
      }
    }
    int d0 = t * 32;
#pragma unroll 4
    for (int dr = 0; dr < 32; dr++) {
      float w = S[bufC + dr * 128 + j];
#pragma unroll
      for (int bb = 0; bb < 4; bb++)
        acc[bb] += S[(bh * 4 + bb) * D_DIM + d0 + dr] * w;
    }
    __syncthreads();
  }

#pragma unroll
  for (int bb = 0; bb < 4; bb++) {
    float h = fmaxf(acc[bb], 0.f) * rg2[j] + rbe2[j];
    S[13312 + (bh * 4 + bb) * 128 + j] = h;
  }
  __syncthreads();

#pragma unroll
  for (int c = 0; c < 8; c++) {
    int e = c * 256 + tid;
    gl_lds16((const char*)rw2 + e * 16, (char*)&S[0] + e * 16);
  }
#pragma unroll
  for (int i = 0; i < 4; i++) {
    int e = i * 256 + tid;
    S[8192 + e] = h1m[bO * 128 + e];
  }
  __syncthreads();

  {
    const int n = tid & 63, bg = tid >> 6;
#pragma unroll
    for (int bb = 0; bb < 2; bb++) {
      int b = bg * 2 + bb;
      float a = rb2[n];
#pragma unroll 8
      for (int jj = 0; jj < 128; jj++) a += S[13312 + b * 128 + jj] * S[jj * 64 + n];
      S[10240 + b * 64 + n] = fmaxf(a, 0.f) * rg3[n] + rbe3[n];
    }
  }
  __syncthreads();

#pragma unroll
  for (int c = 0; c < 8; c++) {
    int e = c * 256 + tid;
    gl_lds16((const char*)hw2 + e * 16, (char*)&S[0] + e * 16);
  }

#pragma unroll
  for (int i = 0; i < 2; i++) {
    int b = wave * 2 + i;
    float v = S[10240 + b * 64 + lane] * rw3[lane];
#pragma unroll
    for (int off = 32; off > 0; off >>= 1) v += __shfl_xor(v, off);
    if (lane == 0) S[11264 + b] = sigmoidf(v + rb3[0]);
  }
  __syncthreads();

  {
    const int n = tid & 63, bg = tid >> 6;
#pragma unroll
    for (int bb = 0; bb < 2; bb++) {
      int b = bg * 2 + bb;
      float a = hb2[n];
#pragma unroll 8
      for (int jj = 0; jj < 128; jj++) a += S[8192 + b * 128 + jj] * S[jj * 64 + n];
      S[10752 + b * 64 + n] = fmaxf(a, 0.f) * hg3[n] + hbe3[n];
    }
  }
  __syncthreads();

#pragma unroll
  for (int i = 0; i < 2; i++) {
    int b = wave * 2 + i;
    float v = S[10752 + b * 64 + lane] * hw3[lane];
#pragma unroll
    for (int off = 32; off > 0; off >>= 1) v += __shfl_xor(v, off);
    if (lane == 0) S[11272 + b] = sigmoidf(v + hb3[0]);
  }
  __syncthreads();

  if (tid < 8) {
    int b = bO + tid;
    out[b] = 0.5f * (S[11264 + tid] + S[11272 + tid]) + amean[b];
  }
}

// ---------------- launch ----------------
extern "C" void kernel_launch(void* const* d_in, const int* in_sizes, int n_in,
                              void* d_out, int out_size, void* d_ws, size_t ws_size,
                              hipStream_t stream) {
  const float* q_patch = (const float*)d_in[0];
  const float* r_patch = (const float*)d_in[1];
  const float* q_img   = (const float*)d_in[2];
  const float* r_img   = (const float*)d_in[3];
  const float* adpt_w1 = (const float*)d_in[4];
  const float* adpt_w2 = (const float*)d_in[5];
  const float* dh_w1 = (const float*)d_in[6];
  const float* dh_b1 = (const float*)d_in[7];
  const float* dh_g2 = (const float*)d_in[8];
  const float* dh_be2 = (const float*)d_in[9];
  const float* dh_w2 = (const float*)d_in[10];
  const float* dh_b2 = (const float*)d_in[11];
  const float* dh_g3 = (const float*)d_in[12];
  const float* dh_be3 = (const float*)d_in[13];
  const float* dh_w3 = (const float*)d_in[14];
  const float* dh_b3 = (const float*)d_in[15];
  const float* dr_w1 = (const float*)d_in[16];
  const float* dr_b1 = (const float*)d_in[17];
  const float* dr_g2 = (const float*)d_in[18];
  const float* dr_be2 = (const float*)d_in[19];
  const float* dr_w2 = (const float*)d_in[20];
  const float* dr_b2 = (const float*)d_in[21];
  const float* dr_g3 = (const float*)d_in[22];
  const float* dr_be3 = (const float*)d_in[23];
  const float* dr_w3 = (const float*)d_in[24];
  const float* dr_b3 = (const float*)d_in[25];

  // ws layout (bytes) — fp8 staging buffers
  const size_t QB_BYTES = (size_t)MPAD * D_DIM;   // 9,338,880
  const size_t RB_BYTES = (size_t)NPAD * D_DIM;   // 2,457,600
  char* ws = (char*)d_ws;
  unsigned char* qb = (unsigned char*)(ws);
  unsigned char* rb = (unsigned char*)(ws + QB_BYTES);
  float* qinv        = (float*)(ws + QB_BYTES + RB_BYTES);
  unsigned* rowmax   = (unsigned*)(ws + QB_BYTES + RB_BYTES + (size_t)M_REAL * 4);
  float* h1          = (float*)(ws + QB_BYTES + RB_BYTES + (size_t)M_REAL * 4 + (size_t)MPAD * 4);
  float* favg        = h1 + 16 * 160;
  float* h1m         = favg + D_DIM;
  float* amean       = h1m + 64 * 128;

  stage_all_kernel<<<ABLKS + QBLKS + RBLKS, 256, 0, stream>>>(
      q_patch, r_patch, r_img, adpt_w1, qb, rb, qinv, rowmax, h1);
  sim_max_kernel<<<8 * MC * NTILES, 512, 0, stream>>>(qb, rb, rowmax);
  tail1_kernel<<<18, 256, 0, stream>>>(
      h1, adpt_w2, rowmax, qinv, dh_w1, dh_b1, dh_g2, dh_be2,
      favg, h1m, amean);
  tail2_kernel<<<8, 256, 0, stream>>>(
      q_img, favg, h1m, amean,
      dh_w2, dh_b2, dh_g3, dh_be3, dh_w3, dh_b3,
      dr_w1, dr_b1, dr_g2, dr_be2, dr_w2, dr_b2, dr_g3, dr_be3, dr_w3, dr_b3,
      (float*)d_out);
}

// Round 4
// 399.698 us; speedup vs baseline: 1.0293x; 1.0293x over previous
//
#include <hip/hip_runtime.h>
#include <stdint.h>

// ---------------- problem dims ----------------
#define B_DIM 64
#define P_DIM 225
#define K_DIM 16
#define D_DIM 640
#define M_REAL (B_DIM * P_DIM)   // 14400 query rows
#define N_REAL (K_DIM * P_DIM)   // 3600 reference rows

// ---------------- GEMM tiling (256x256, 8-phase schedule) ----------------
#define BM 256
#define BN 256
#define MTILES 57                // ceil(14400/256) -> Mpad 14592
#define NTILES 15                // ceil(3600/256)  -> Npad 3840
#define MPAD (MTILES * BM)
#define NPAD (NTILES * BN)
#define MC 8                     // ceil(MTILES/8) per-XCD bm groups

typedef float f32x4 __attribute__((ext_vector_type(4)));
typedef int   i32x4 __attribute__((ext_vector_type(4)));
typedef int   i32x8 __attribute__((ext_vector_type(8)));

// ---------------- helpers ----------------
// float -> OCP e4m3 byte (v_cvt_pk_fp8_f32)
__device__ __forceinline__ unsigned char f2fp8(float f) {
  int r = __builtin_amdgcn_cvt_pk_fp8_f32(f, f, 0, false);
  return (unsigned char)(r & 0xFF);
}

// monotone float -> uint key (order-preserving), for atomicMax on floats
__device__ __forceinline__ unsigned f2key(float f) {
  union { float f; unsigned u; } v; v.f = f;
  unsigned u = v.u;
  return (u & 0x80000000u) ? ~u : (u | 0x80000000u);
}
__device__ __forceinline__ float key2f(unsigned k) {
  unsigned b = (k & 0x80000000u) ? (k ^ 0x80000000u) : ~k;
  union { unsigned u; float f; } v; v.u = b;
  return v.f;
}

__device__ __forceinline__ void gl_lds16(const void* g, void* l) {
  __builtin_amdgcn_global_load_lds(
      (const __attribute__((address_space(1))) void*)g,
      (__attribute__((address_space(3))) void*)l,
      16, 0, 0);
}

__device__ __forceinline__ float sigmoidf(float x) {
  return 1.f / (1.f + expf(-x));
}

// =====================================================================
// Kernel A: staging (fp8 e4m3 outputs) — pad sizes track MPAD/NPAD.
// =====================================================================
#define QBLKS (MPAD / 4)
#define RBLKS (NPAD / 4)
#define ABLKS 16
__global__ __launch_bounds__(256) void stage_all_kernel(
    const float* __restrict__ q, const float* __restrict__ r,
    const float* __restrict__ r_img, const float* __restrict__ aw1,
    unsigned char* __restrict__ qb, unsigned char* __restrict__ rb,
    float* __restrict__ qinv, unsigned* __restrict__ rowmax,
    float* __restrict__ h1) {
  const int blk = blockIdx.x;
  const int tid = threadIdx.x;

  if (blk < ABLKS) {
    __shared__ float rk_s[D_DIM];
    const int k = blk;
    for (int i = tid; i < D_DIM; i += 256) rk_s[i] = r_img[k * D_DIM + i];
    __syncthreads();
    if (tid < 160) {
      const int j = tid;
      float a = 0.f;
#pragma unroll 8
      for (int d = 0; d < D_DIM; d++) a += rk_s[d] * aw1[d * 160 + j];
      h1[k * 160 + j] = fmaxf(a, 0.f);
    }
    return;
  }

  if (blk < ABLKS + QBLKS) {
    int row = (blk - ABLKS) * 4 + (tid >> 6);
    int lane = tid & 63;
    if (lane == 0) rowmax[row] = 0u;
    unsigned char* dst = qb + (long)row * D_DIM;
    if (row >= M_REAL) {
#pragma unroll
      for (int i = 0; i < 10; i++) dst[i * 64 + lane] = 0;
      return;
    }
    const float* src = q + (long)row * D_DIM;
    float v[10];
    float ss = 0.f;
#pragma unroll
    for (int i = 0; i < 10; i++) { v[i] = src[i * 64 + lane]; ss += v[i] * v[i]; }
#pragma unroll
    for (int off = 32; off > 0; off >>= 1) ss += __shfl_xor(ss, off);
    float inv = 1.f / (sqrtf(ss) + 1e-6f);
    if (lane == 0) qinv[row] = inv * (1.f / 16.f);  // fold r-scale
#pragma unroll
    for (int i = 0; i < 10; i++) dst[i * 64 + lane] = f2fp8(v[i]);
    return;
  }

  {
    int row = (blk - ABLKS - QBLKS) * 4 + (tid >> 6);
    int lane = tid & 63;
    unsigned char* dst = rb + (long)row * D_DIM;
    if (row >= N_REAL) {
#pragma unroll
      for (int i = 0; i < 10; i++) dst[i * 64 + lane] = 0;
      return;
    }
    const float* src = r + (long)row * D_DIM;
    float v[10];
    float ss = 0.f;
#pragma unroll
    for (int i = 0; i < 10; i++) { v[i] = src[i * 64 + lane]; ss += v[i] * v[i]; }
#pragma unroll
    for (int off = 32; off > 0; off >>= 1) ss += __shfl_xor(ss, off);
    float sc = 16.f / (sqrtf(ss) + 1e-6f);   // normalize, x16 into e4m3 normals
#pragma unroll
    for (int i = 0; i < 10; i++) dst[i * 64 + lane] = f2fp8(v[i] * sc);
  }
}

// =====================================================================
// Kernel B: 256x256 MX-fp8 MFMA GEMM + row-max, 8-phase schedule.
//   ROUND-4 FIX: __launch_bounds__(512, 1).  Round 3's (512,2) capped
//   the allocator at 128 VGPR (2 waves/EU x 8-wave block) while
//   acc[8][4] f32x4 alone is 128 VGPR -> accumulators spilled to
//   scratch (FETCH 276MB / WRITE 453MB of spill traffic, 3.4x slower).
//   LDS is 128 KB -> 1 block/CU regardless, so (,,2) bought nothing.
//   m201's template runs this exact geometry at 249 VGPR, 0 spill.
// =====================================================================
__global__ __launch_bounds__(512, 1) void sim_max_kernel(
    const unsigned char* __restrict__ Qb,
    const unsigned char* __restrict__ Rb,
    unsigned* __restrict__ rowmax) {
  __shared__ __attribute__((aligned(16))) unsigned char As[2][BM * 128];  // 2x32 KB
  __shared__ __attribute__((aligned(16))) unsigned char Bs[2][BN * 128];  // 2x32 KB

  const int xcd = blockIdx.x & 7;
  const int idx = blockIdx.x >> 3;
  const int bm = xcd + 8 * (idx % MC);
  const int bn = idx / MC;
  if (bm >= MTILES) return;

  const int tid = threadIdx.x;
  const int lane = tid & 63;
  const int wave = tid >> 6;
  const int wr = wave >> 2, wc = wave & 3;   // 2 x 4 wave grid
  const int q = lane >> 4, m0 = lane & 15;   // k-chunk (32B) / frag row

  // ---- staging geometry: 512 threads cover 64 rows x 8 chunks (8 KB) ----
  const int sRow = tid >> 3;                 // 0..63
  const int sp = tid & 7;                    // phys 16B chunk
  const int sSrcC = (sp ^ (sRow & 7)) << 4;  // pre-swizzled source byte
  const int sLds = tid * 16;                 // linear LDS dest within quarter

  // ---- frag read LDS byte offsets (row&7 == m0&7 for all mi/ni) ----
  const int r7 = m0 & 7;
  const int cLo = (((q << 1) | 0) ^ r7) << 4;
  const int cHi = (((q << 1) | 1) ^ r7) << 4;

  const int aBase = bm * BM;
  const int bBase = bn * BN;

  f32x4 zero = {0.f, 0.f, 0.f, 0.f};
  f32x4 acc[8][4];
#pragma unroll
  for (int i = 0; i < 8; i++)
#pragma unroll
    for (int j = 0; j < 4; j++) acc[i][j] = zero;

  union frag_u { i32x8 v; i32x4 h[2]; };

  // stage quarter P (A rows P*64..+63 and B same) of K-tile KT into buffer BUF
#define STAGE_Q(KT, P, BUF)                                                   \
  {                                                                           \
    const int row_ = (P) * 64 + sRow;                                         \
    gl_lds16(Qb + (size_t)(aBase + row_) * D_DIM + (KT) * 128 + sSrcC,        \
             &As[BUF][(P) * 8192 + sLds]);                                    \
    gl_lds16(Rb + (size_t)(bBase + row_) * D_DIM + (KT) * 128 + sSrcC,        \
             &Bs[BUF][(P) * 8192 + sLds]);                                    \
  }

  // prologue: stage full tile 0 into buf 0, gate
  STAGE_Q(0, 0, 0); STAGE_Q(0, 1, 0); STAGE_Q(0, 2, 0); STAGE_Q(0, 3, 0);
  asm volatile("s_waitcnt vmcnt(0)" ::: "memory");
  __builtin_amdgcn_s_barrier();

  frag_u bf[4];

#pragma unroll
  for (int kt = 0; kt < 5; kt++) {
    const int cur = kt & 1;
#pragma unroll
    for (int p = 0; p < 4; p++) {
      // ---- ds-region: frag reads + next-tile quarter prefetch ----
      if (p == 0) {
#pragma unroll
        for (int ni = 0; ni < 4; ni++) {
          const int rb_ = (wc * 64 + ni * 16 + m0) * 128;
          bf[ni].h[0] = *(const i32x4*)&Bs[cur][rb_ + cLo];
          bf[ni].h[1] = *(const i32x4*)&Bs[cur][rb_ + cHi];
        }
      }
      frag_u af0, af1;
      {
        const int r0 = (wr * 128 + (2 * p + 0) * 16 + m0) * 128;
        const int r1 = (wr * 128 + (2 * p + 1) * 16 + m0) * 128;
        af0.h[0] = *(const i32x4*)&As[cur][r0 + cLo];
        af0.h[1] = *(const i32x4*)&As[cur][r0 + cHi];
        af1.h[0] = *(const i32x4*)&As[cur][r1 + cLo];
        af1.h[1] = *(const i32x4*)&As[cur][r1 + cHi];
      }
      if (kt < 4) STAGE_Q(kt + 1, p, cur ^ 1);

      __builtin_amdgcn_s_barrier();   // pre-MFMA barrier (phase split)

      __builtin_amdgcn_s_setprio(1);
#pragma unroll
      for (int ni = 0; ni < 4; ni++)
        acc[2 * p + 0][ni] = __builtin_amdgcn_mfma_scale_f32_16x16x128_f8f6f4(
            af0.v, bf[ni].v, acc[2 * p + 0][ni],
            0, 0, 0, 0x7F7F7F7Fu, 0, 0x7F7F7F7Fu);
#pragma unroll
      for (int ni = 0; ni < 4; ni++)
        acc[2 * p + 1][ni] = __builtin_amdgcn_mfma_scale_f32_16x16x128_f8f6f4(
            af1.v, bf[ni].v, acc[2 * p + 1][ni],
            0, 0, 0, 0x7F7F7F7Fu, 0, 0x7F7F7F7Fu);
      __builtin_amdgcn_s_setprio(0);

      // K-tile boundary: drain the tile we just finished prefetching
      // (issued across the 4 phases -> ~1 phase of slack on the last one)
      if (p == 3 && kt < 4) asm volatile("s_waitcnt vmcnt(0)" ::: "memory");
      if (!(p == 3 && kt == 4)) __builtin_amdgcn_s_barrier();  // post-MFMA
    }
  }
#undef STAGE_Q

  // epilogue: per-row max over this block's 256 columns, then global atomicMax
  // (C/D layout for 16x16 shapes: col = lane&15, row = (lane>>4)*4 + reg)
  const int colBase = bn * BN + wc * 64;
#pragma unroll
  for (int mi = 0; mi < 8; mi++) {
    float rmax[4] = {-3.0e38f, -3.0e38f, -3.0e38f, -3.0e38f};
#pragma unroll
    for (int ni = 0; ni < 4; ni++) {
      bool valid = (colBase + ni * 16 + m0) < N_REAL;
#pragma unroll
      for (int r = 0; r < 4; r++) {
        float v = valid ? acc[mi][ni][r] : -3.0e38f;
        rmax[r] = fmaxf(rmax[r], v);
      }
    }
#pragma unroll
    for (int r = 0; r < 4; r++) {
      float v = rmax[r];
      v = fmaxf(v, __shfl_xor(v, 1));
      v = fmaxf(v, __shfl_xor(v, 2));
      v = fmaxf(v, __shfl_xor(v, 4));
      v = fmaxf(v, __shfl_xor(v, 8));
      rmax[r] = v;
    }
    if (m0 == 0) {
      int row = bm * BM + wr * 128 + mi * 16 + q * 4;
#pragma unroll
      for (int r = 0; r < 4; r++)
        atomicMax(&rowmax[row + r], f2key(rmax[r]));
    }
  }
}

// =====================================================================
// Kernel T1: tail part 1 (unchanged).
// =====================================================================
__global__ __launch_bounds__(256) void tail1_kernel(
    const float* __restrict__ h1, const float* __restrict__ aw2,
    const unsigned* __restrict__ rowmax, const float* __restrict__ qinv,
    const float* __restrict__ hw1, const float* __restrict__ hb1,
    const float* __restrict__ hg2, const float* __restrict__ hbe2,
    float* __restrict__ favg, float* __restrict__ h1m,
    float* __restrict__ amean) {
  __shared__ __attribute__((aligned(16))) float S[12800];  // 51.2 KB
  const int blk = blockIdx.x;
  const int tid = threadIdx.x;
  const int wave = tid >> 6, lane = tid & 63;

  if (blk < 10) {
    const int d0 = blk * 64;
#pragma unroll
    for (int i = 0; i < 10; i++) S[i * 256 + tid] = h1[i * 256 + tid];
#pragma unroll
    for (int c = 0; c < 10; c++) {
      int e = c * 256 + tid;
      int row = e >> 4, col16 = e & 15;
      gl_lds16((const char*)aw2 + (size_t)row * D_DIM * 4 + d0 * 4 + col16 * 16,
               (char*)&S[2560] + e * 16);
    }
    __syncthreads();

    const int d = tid & 63, kg = tid >> 6;
    float a0 = 0.f, a1 = 0.f, a2 = 0.f, a3 = 0.f;
#pragma unroll 8
    for (int j = 0; j < 160; j++) {
      float w = S[2560 + j * 64 + d];
      a0 += S[(kg * 4 + 0) * 160 + j] * w;
      a1 += S[(kg * 4 + 1) * 160 + j] * w;
      a2 += S[(kg * 4 + 2) * 160 + j] * w;
      a3 += S[(kg * 4 + 3) * 160 + j] * w;
    }
    float p = fmaxf(a0, 0.f) + fmaxf(a1, 0.f) + fmaxf(a2, 0.f) + fmaxf(a3, 0.f);
    __syncthreads();
    S[kg * 64 + d] = p;
    __syncthreads();
    if (kg == 0)
      favg[d0 + d] = (S[d] + S[64 + d] + S[128 + d] + S[192 + d]) * (1.f / 16.f);
    return;
  }

  const int bO = (blk - 10) * 8;
  for (int e = tid; e < 8 * P_DIM; e += 256) {
    int row = bO * P_DIM + e;
    float mx = key2f(rowmax[row]);
    S[e] = 0.5f * (1.f - mx * qinv[row]);
  }
  __syncthreads();

#pragma unroll
  for (int i = 0; i < 2; i++) {
    int b = wave * 2 + i;
    float s = S[b * P_DIM + lane];
    s += S[b * P_DIM + lane + 64];
    s += S[b * P_DIM + lane + 128];
    if (lane < 33) s += S[b * P_DIM + lane + 192];
#pragma unroll
    for (int off = 32; off > 0; off >>= 1) s += __shfl_xor(s, off);
    if (lane == 0) amean[bO + b] = s * (1.f / 225.f);
  }

  const int j = tid & 127, bh = tid >> 7;
  float acc[4];
#pragma unroll
  for (int bb = 0; bb < 4; bb++) acc[bb] = hb1[j];

  for (int t = 0; t < 7; t++) {
    int p0 = t * 32;
#pragma unroll
    for (int c = 0; c < 4; c++) {
      int e = c * 256 + tid;
      int row = e >> 5, col16 = e & 31;
      gl_lds16((const char*)hw1 + (size_t)(p0 + row) * 128 * 4 + col16 * 16,
               (char*)&S[1800] + e * 16);
    }
    __syncthreads();
#pragma unroll 4
    for (int pr = 0; pr < 32; pr++) {
      float w = S[1800 + pr * 128 + j];
#pragma unroll
      for (int bb = 0; bb < 4; bb++)
        acc[bb] += S[(bh * 4 + bb) * P_DIM + p0 + pr] * w;
    }
    __syncthreads();
  }
  {
    float w = hw1[224 * 128 + j];
#pragma unroll
    for (int bb = 0; bb < 4; bb++)
      acc[bb] += S[(bh * 4 + bb) * P_DIM + 224] * w;
  }
#pragma unroll
  for (int bb = 0; bb < 4; bb++) {
    float h = fmaxf(acc[bb], 0.f) * hg2[j] + hbe2[j];
    h1m[(bO + bh * 4 + bb) * 128 + j] = h;
  }
}

// =====================================================================
// Kernel T2: tail part 2 (unchanged).
// =====================================================================
__global__ __launch_bounds__(256) void tail2_kernel(
    const float* __restrict__ q_img, const float* __restrict__ favg,
    const float* __restrict__ h1m, const float* __restrict__ amean,
    const float* __restrict__ hw2, const float* __restrict__ hb2,
    const float* __restrict__ hg3, const float* __restrict__ hbe3,
    const float* __restrict__ hw3, const float* __restrict__ hb3,
    const float* __restrict__ rw1, const float* __restrict__ rb1,
    const float* __restrict__ rg2, const float* __restrict__ rbe2,
    const float* __restrict__ rw2, const float* __restrict__ rb2,
    const float* __restrict__ rg3, const float* __restrict__ rbe3,
    const float* __restrict__ rw3, const float* __restrict__ rb3,
    float* __restrict__ out) {
  __shared__ __attribute__((aligned(16))) float S[14336];  // 57.3 KB
  const int tid = threadIdx.x;
  const int wave = tid >> 6, lane = tid & 63;
  const int bO = blockIdx.x * 8;

#pragma unroll
  for (int i = 0; i < 20; i++) {
    int e = i * 256 + tid;
    int d = e % D_DIM;
    S[e] = q_img[bO * D_DIM + e] - favg[d];
  }

#pragma unroll
  for (int c = 0; c < 4; c++) {
    int e = c * 256 + tid;
    int row = e >> 5, col16 = e & 31;
    gl_lds16((const char*)rw1 + (size_t)row * 128 * 4 + col16 * 16,
             (char*)&S[5120] + e * 16);
  }
  __syncthreads();

  const int j = tid & 127, bh = tid >> 7;
  float acc[4];
#pragma unroll
  for (int bb = 0; bb < 4; bb++) acc[bb] = rb1[j];

  for (int t = 0; t < 20; t++) {
    int bufC = 5120 + (t & 1) * 4096;
    int bufN = 5120 + ((t + 1) & 1) * 4096;
    if (t < 19) {
      int d0n = (t + 1) * 32;
#pragma unroll
      for (int c = 0; c < 4; c++) {
        int e = c * 256 + tid;
        int row = e >> 5, col16 = e & 31;
        gl_lds16((const char*)rw1 + (size_t)(d0n + row) * 128 * 4 + col16 * 16,
                 (char*)&S[bufN] + e * 16);
      }
    }
    int d0 = t * 32;
#pragma unroll 4
    for (int dr = 0; dr < 32; dr++) {
      float w = S[bufC + dr * 128 + j];
#pragma unroll
      for (int bb = 0; bb < 4; bb++)
        acc[bb] += S[(bh * 4 + bb) * D_DIM + d0 + dr] * w;
    }
    __syncthreads();
  }

#pragma unroll
  for (int bb = 0; bb < 4; bb++) {
    float h = fmaxf(acc[bb], 0.f) * rg2[j] + rbe2[j];
    S[13312 + (bh * 4 + bb) * 128 + j] = h;
  }
  __syncthreads();

#pragma unroll
  for (int c = 0; c < 8; c++) {
    int e = c * 256 + tid;
    gl_lds16((const char*)rw2 + e * 16, (char*)&S[0] + e * 16);
  }
#pragma unroll
  for (int i = 0; i < 4; i++) {
    int e = i * 256 + tid;
    S[8192 + e] = h1m[bO * 128 + e];
  }
  __syncthreads();

  {
    const int n = tid & 63, bg = tid >> 6;
#pragma unroll
    for (int bb = 0; bb < 2; bb++) {
      int b = bg * 2 + bb;
      float a = rb2[n];
#pragma unroll 8
      for (int jj = 0; jj < 128; jj++) a += S[13312 + b * 128 + jj] * S[jj * 64 + n];
      S[10240 + b * 64 + n] = fmaxf(a, 0.f) * rg3[n] + rbe3[n];
    }
  }
  __syncthreads();

#pragma unroll
  for (int c = 0; c < 8; c++) {
    int e = c * 256 + tid;
    gl_lds16((const char*)hw2 + e * 16, (char*)&S[0] + e * 16);
  }

#pragma unroll
  for (int i = 0; i < 2; i++) {
    int b = wave * 2 + i;
    float v = S[10240 + b * 64 + lane] * rw3[lane];
#pragma unroll
    for (int off = 32; off > 0; off >>= 1) v += __shfl_xor(v, off);
    if (lane == 0) S[11264 + b] = sigmoidf(v + rb3[0]);
  }
  __syncthreads();

  {
    const int n = tid & 63, bg = tid >> 6;
#pragma unroll
    for (int bb = 0; bb < 2; bb++) {
      int b = bg * 2 + bb;
      float a = hb2[n];
#pragma unroll 8
      for (int jj = 0; jj < 128; jj++) a += S[8192 + b * 128 + jj] * S[jj * 64 + n];
      S[10752 + b * 64 + n] = fmaxf(a, 0.f) * hg3[n] + hbe3[n];
    }
  }
  __syncthreads();

#pragma unroll
  for (int i = 0; i < 2; i++) {
    int b = wave * 2 + i;
    float v = S[10752 + b * 64 + lane] * hw3[lane];
#pragma unroll
    for (int off = 32; off > 0; off >>= 1) v += __shfl_xor(v, off);
    if (lane == 0) S[11272 + b] = sigmoidf(v + hb3[0]);
  }
  __syncthreads();

  if (tid < 8) {
    int b = bO + tid;
    out[b] = 0.5f * (S[11264 + tid] + S[11272 + tid]) + amean[b];
  }
}

// ---------------- launch ----------------
extern "C" void kernel_launch(void* const* d_in, const int* in_sizes, int n_in,
                              void* d_out, int out_size, void* d_ws, size_t ws_size,
                              hipStream_t stream) {
  const float* q_patch = (const float*)d_in[0];
  const float* r_patch = (const float*)d_in[1];
  const float* q_img   = (const float*)d_in[2];
  const float* r_img   = (const float*)d_in[3];
  const float* adpt_w1 = (const float*)d_in[4];
  const float* adpt_w2 = (const float*)d_in[5];
  const float* dh_w1 = (const float*)d_in[6];
  const float* dh_b1 = (const float*)d_in[7];
  const float* dh_g2 = (const float*)d_in[8];
  const float* dh_be2 = (const float*)d_in[9];
  const float* dh_w2 = (const float*)d_in[10];
  const float* dh_b2 = (const float*)d_in[11];
  const float* dh_g3 = (const float*)d_in[12];
  const float* dh_be3 = (const float*)d_in[13];
  const float* dh_w3 = (const float*)d_in[14];
  const float* dh_b3 = (const float*)d_in[15];
  const float* dr_w1 = (const float*)d_in[16];
  const float* dr_b1 = (const float*)d_in[17];
  const float* dr_g2 = (const float*)d_in[18];
  const float* dr_be2 = (const float*)d_in[19];
  const float* dr_w2 = (const float*)d_in[20];
  const float* dr_b2 = (const float*)d_in[21];
  const float* dr_g3 = (const float*)d_in[22];
  const float* dr_be3 = (const float*)d_in[23];
  const float* dr_w3 = (const float*)d_in[24];
  const float* dr_b3 = (const float*)d_in[25];

  // ws layout (bytes) — fp8 staging buffers
  const size_t QB_BYTES = (size_t)MPAD * D_DIM;   // 9,338,880
  const size_t RB_BYTES = (size_t)NPAD * D_DIM;   // 2,457,600
  char* ws = (char*)d_ws;
  unsigned char* qb = (unsigned char*)(ws);
  unsigned char* rb = (unsigned char*)(ws + QB_BYTES);
  float* qinv        = (float*)(ws + QB_BYTES + RB_BYTES);
  unsigned* rowmax   = (unsigned*)(ws + QB_BYTES + RB_BYTES + (size_t)M_REAL * 4);
  float* h1          = (float*)(ws + QB_BYTES + RB_BYTES + (size_t)M_REAL * 4 + (size_t)MPAD * 4);
  float* favg        = h1 + 16 * 160;
  float* h1m         = favg + D_DIM;
  float* amean       = h1m + 64 * 128;

  stage_all_kernel<<<ABLKS + QBLKS + RBLKS, 256, 0, stream>>>(
      q_patch, r_patch, r_img, adpt_w1, qb, rb, qinv, rowmax, h1);
  sim_max_kernel<<<8 * MC * NTILES, 512, 0, stream>>>(qb, rb, rowmax);
  tail1_kernel<<<18, 256, 0, stream>>>(
      h1, adpt_w2, rowmax, qinv, dh_w1, dh_b1, dh_g2, dh_be2,
      favg, h1m, amean);
  tail2_kernel<<<8, 256, 0, stream>>>(
      q_img, favg, h1m, amean,
      dh_w2, dh_b2, dh_g3, dh_be3, dh_w3, dh_b3,
      dr_w1, dr_b1, dr_g2, dr_be2, dr_w2, dr_b2, dr_g3, dr_be3, dr_w3, dr_b3,
      (float*)d_out);
}

// Round 5
// 332.129 us; speedup vs baseline: 1.2387x; 1.2034x over previous
//
#include <hip/hip_runtime.h>
#include <stdint.h>

// ---------------- problem dims ----------------
#define B_DIM 64
#define P_DIM 225
#define K_DIM 16
#define D_DIM 640
#define M_REAL (B_DIM * P_DIM)   // 14400 query rows
#define N_REAL (K_DIM * P_DIM)   // 3600 reference rows

// ---------------- GEMM tiling (256x256, 8-phase, 16 waves) ----------------
#define BM 256
#define BN 256
#define MTILES 57                // ceil(14400/256) -> Mpad 14592
#define NTILES 15                // ceil(3600/256)  -> Npad 3840
#define MPAD (MTILES * BM)
#define NPAD (NTILES * BN)
#define MC 8                     // ceil(MTILES/8) per-XCD bm groups

typedef float f32x4 __attribute__((ext_vector_type(4)));
typedef int   i32x4 __attribute__((ext_vector_type(4)));
typedef int   i32x8 __attribute__((ext_vector_type(8)));

// ---------------- helpers ----------------
// float -> OCP e4m3 byte (v_cvt_pk_fp8_f32)
__device__ __forceinline__ unsigned char f2fp8(float f) {
  int r = __builtin_amdgcn_cvt_pk_fp8_f32(f, f, 0, false);
  return (unsigned char)(r & 0xFF);
}

// monotone float -> uint key (order-preserving), for atomicMax on floats
__device__ __forceinline__ unsigned f2key(float f) {
  union { float f; unsigned u; } v; v.f = f;
  unsigned u = v.u;
  return (u & 0x80000000u) ? ~u : (u | 0x80000000u);
}
__device__ __forceinline__ float key2f(unsigned k) {
  unsigned b = (k & 0x80000000u) ? (k ^ 0x80000000u) : ~k;
  union { unsigned u; float f; } v; v.u = b;
  return v.f;
}

__device__ __forceinline__ void gl_lds16(const void* g, void* l) {
  __builtin_amdgcn_global_load_lds(
      (const __attribute__((address_space(1))) void*)g,
      (__attribute__((address_space(3))) void*)l,
      16, 0, 0);
}

__device__ __forceinline__ float sigmoidf(float x) {
  return 1.f / (1.f + expf(-x));
}

// =====================================================================
// Kernel A: staging (fp8 e4m3 outputs) — pad sizes track MPAD/NPAD.
// =====================================================================
#define QBLKS (MPAD / 4)
#define RBLKS (NPAD / 4)
#define ABLKS 16
__global__ __launch_bounds__(256) void stage_all_kernel(
    const float* __restrict__ q, const float* __restrict__ r,
    const float* __restrict__ r_img, const float* __restrict__ aw1,
    unsigned char* __restrict__ qb, unsigned char* __restrict__ rb,
    float* __restrict__ qinv, unsigned* __restrict__ rowmax,
    float* __restrict__ h1) {
  const int blk = blockIdx.x;
  const int tid = threadIdx.x;

  if (blk < ABLKS) {
    __shared__ float rk_s[D_DIM];
    const int k = blk;
    for (int i = tid; i < D_DIM; i += 256) rk_s[i] = r_img[k * D_DIM + i];
    __syncthreads();
    if (tid < 160) {
      const int j = tid;
      float a = 0.f;
#pragma unroll 8
      for (int d = 0; d < D_DIM; d++) a += rk_s[d] * aw1[d * 160 + j];
      h1[k * 160 + j] = fmaxf(a, 0.f);
    }
    return;
  }

  if (blk < ABLKS + QBLKS) {
    int row = (blk - ABLKS) * 4 + (tid >> 6);
    int lane = tid & 63;
    if (lane == 0) rowmax[row] = 0u;
    unsigned char* dst = qb + (long)row * D_DIM;
    if (row >= M_REAL) {
#pragma unroll
      for (int i = 0; i < 10; i++) dst[i * 64 + lane] = 0;
      return;
    }
    const float* src = q + (long)row * D_DIM;
    float v[10];
    float ss = 0.f;
#pragma unroll
    for (int i = 0; i < 10; i++) { v[i] = src[i * 64 + lane]; ss += v[i] * v[i]; }
#pragma unroll
    for (int off = 32; off > 0; off >>= 1) ss += __shfl_xor(ss, off);
    float inv = 1.f / (sqrtf(ss) + 1e-6f);
    if (lane == 0) qinv[row] = inv * (1.f / 16.f);  // fold r-scale
#pragma unroll
    for (int i = 0; i < 10; i++) dst[i * 64 + lane] = f2fp8(v[i]);
    return;
  }

  {
    int row = (blk - ABLKS - QBLKS) * 4 + (tid >> 6);
    int lane = tid & 63;
    unsigned char* dst = rb + (long)row * D_DIM;
    if (row >= N_REAL) {
#pragma unroll
      for (int i = 0; i < 10; i++) dst[i * 64 + lane] = 0;
      return;
    }
    const float* src = r + (long)row * D_DIM;
    float v[10];
    float ss = 0.f;
#pragma unroll
    for (int i = 0; i < 10; i++) { v[i] = src[i * 64 + lane]; ss += v[i] * v[i]; }
#pragma unroll
    for (int off = 32; off > 0; off >>= 1) ss += __shfl_xor(ss, off);
    float sc = 16.f / (sqrtf(ss) + 1e-6f);   // normalize, x16 into e4m3 normals
#pragma unroll
    for (int i = 0; i < 10; i++) dst[i * 64 + lane] = f2fp8(v[i] * sc);
  }
}

// =====================================================================
// Kernel B: 256x256 MX-fp8 MFMA GEMM + row-max.  16 waves (1024 thr),
//   4x4 wave grid, per-wave 64x64 output -> acc[4][4] f32x4 — the
//   EXACT register footprint proven spill-free in rounds 1-2 (88 VGPR,
//   acc in AGPRs).  Rounds 3-4's 8-wave variant (acc[8][4] = 128 f32)
//   spilled to scratch (WRITE 453MB) and the scratch writes evicted
//   the L2 panels (FETCH 276MB) — root cause of the 204us regression.
//   8-phase schedule kept: per phase {2 ds_read_b128 A-frag (+8 B at
//   p0) || 1 gl_lds} -> s_barrier -> setprio(1) 4 MFMA setprio(0) ->
//   s_barrier; vmcnt(0) only at K-tile boundary.  All acc/frag indices
//   are macro LITERALS (rule #20: no reliance on unroll heuristics).
// =====================================================================
__global__ __launch_bounds__(1024) void sim_max_kernel(
    const unsigned char* __restrict__ Qb,
    const unsigned char* __restrict__ Rb,
    unsigned* __restrict__ rowmax) {
  __shared__ __attribute__((aligned(16))) unsigned char As[2][BM * 128];  // 2x32 KB
  __shared__ __attribute__((aligned(16))) unsigned char Bs[2][BN * 128];  // 2x32 KB

  const int xcd = blockIdx.x & 7;
  const int idx = blockIdx.x >> 3;
  const int bm = xcd + 8 * (idx % MC);
  const int bn = idx / MC;
  if (bm >= MTILES) return;

  const int tid = threadIdx.x;
  const int lane = tid & 63;
  const int wave = tid >> 6;                 // 0..15
  const int wr = wave >> 2, wc = wave & 3;   // 4 x 4 wave grid
  const int q = lane >> 4, m0 = lane & 15;

  // ---- staging geometry: 1024 threads cover 128 rows x 8 chunks (16 KB) ----
  const int sRow = tid >> 3;                 // 0..127
  const int sp = tid & 7;                    // phys 16B chunk
  const int sSrcC = (sp ^ (sRow & 7)) << 4;  // pre-swizzled source byte
  const int sLds = tid * 16;                 // linear LDS dest within half

  // ---- frag read LDS byte offsets (row&7 == m0&7 for all mi/ni) ----
  const int r7 = m0 & 7;
  const int cLo = (((q << 1) | 0) ^ r7) << 4;
  const int cHi = (((q << 1) | 1) ^ r7) << 4;

  const int aBase = bm * BM;
  const int bBase = bn * BN;

  f32x4 zero = {0.f, 0.f, 0.f, 0.f};
  f32x4 acc[4][4];
#pragma unroll
  for (int i = 0; i < 4; i++)
#pragma unroll
    for (int j = 0; j < 4; j++) acc[i][j] = zero;

  union frag_u { i32x8 v; i32x4 h[2]; };
  frag_u bf[4];

  // piece P of K-tile KT into buffer BUF:
  //   P=0: A rows 0-127, P=1: A rows 128-255, P=2: B rows 0-127, P=3: B 128-255
#define STAGE_PIECE(KT, P, BUF)                                               \
  {                                                                           \
    if ((P) < 2) {                                                            \
      const int row_ = (P) * 128 + sRow;                                      \
      gl_lds16(Qb + (size_t)(aBase + row_) * D_DIM + (KT) * 128 + sSrcC,      \
               &As[BUF][(P) * 16384 + sLds]);                                 \
    } else {                                                                  \
      const int row_ = ((P) - 2) * 128 + sRow;                                \
      gl_lds16(Rb + (size_t)(bBase + row_) * D_DIM + (KT) * 128 + sSrcC,      \
               &Bs[BUF][((P) - 2) * 16384 + sLds]);                           \
    }                                                                         \
  }

#define PHASE(P, CUR, STG, KTN, LASTALL)                                      \
  {                                                                           \
    frag_u af;                                                                \
    {                                                                         \
      const int ra = (wr * 64 + (P) * 16 + m0) * 128;                         \
      af.h[0] = *(const i32x4*)&As[CUR][ra + cLo];                            \
      af.h[1] = *(const i32x4*)&As[CUR][ra + cHi];                            \
    }                                                                         \
    if ((P) == 0) {                                                           \
      _Pragma("unroll")                                                       \
      for (int ni = 0; ni < 4; ni++) {                                        \
        const int rb_ = (wc * 64 + ni * 16 + m0) * 128;                       \
        bf[ni].h[0] = *(const i32x4*)&Bs[CUR][rb_ + cLo];                     \
        bf[ni].h[1] = *(const i32x4*)&Bs[CUR][rb_ + cHi];                     \
      }                                                                       \
    }                                                                         \
    if (STG) STAGE_PIECE(KTN, P, (CUR) ^ 1);                                  \
    __builtin_amdgcn_s_barrier();                                             \
    __builtin_amdgcn_s_setprio(1);                                            \
    _Pragma("unroll")                                                         \
    for (int ni = 0; ni < 4; ni++)                                            \
      acc[P][ni] = __builtin_amdgcn_mfma_scale_f32_16x16x128_f8f6f4(          \
          af.v, bf[ni].v, acc[P][ni], 0, 0, 0, 0x7F7F7F7Fu, 0, 0x7F7F7F7Fu);  \
    __builtin_amdgcn_s_setprio(0);                                            \
    if ((P) == 3 && (STG)) asm volatile("s_waitcnt vmcnt(0)" ::: "memory");   \
    if (!(LASTALL)) __builtin_amdgcn_s_barrier();                             \
  }

#define KTILE(KT, CUR, STG, LAST)                                             \
  PHASE(0, CUR, STG, (KT) + 1, 0)                                             \
  PHASE(1, CUR, STG, (KT) + 1, 0)                                             \
  PHASE(2, CUR, STG, (KT) + 1, 0)                                             \
  PHASE(3, CUR, STG, (KT) + 1, LAST)

  // prologue: stage full tile 0 into buf 0, gate
  STAGE_PIECE(0, 0, 0) STAGE_PIECE(0, 1, 0) STAGE_PIECE(0, 2, 0) STAGE_PIECE(0, 3, 0)
  asm volatile("s_waitcnt vmcnt(0)" ::: "memory");
  __builtin_amdgcn_s_barrier();

  KTILE(0, 0, 1, 0)
  KTILE(1, 1, 1, 0)
  KTILE(2, 0, 1, 0)
  KTILE(3, 1, 1, 0)
  KTILE(4, 0, 0, 1)

#undef KTILE
#undef PHASE
#undef STAGE_PIECE

  // epilogue: per-row max over this block's 256 columns, then global atomicMax
  // (C/D layout for 16x16 shapes: col = lane&15, row = (lane>>4)*4 + reg)
  const int colBase = bn * BN + wc * 64;
#pragma unroll
  for (int mi = 0; mi < 4; mi++) {
    float rmax[4] = {-3.0e38f, -3.0e38f, -3.0e38f, -3.0e38f};
#pragma unroll
    for (int ni = 0; ni < 4; ni++) {
      bool valid = (colBase + ni * 16 + m0) < N_REAL;
#pragma unroll
      for (int r = 0; r < 4; r++) {
        float v = valid ? acc[mi][ni][r] : -3.0e38f;
        rmax[r] = fmaxf(rmax[r], v);
      }
    }
#pragma unroll
    for (int r = 0; r < 4; r++) {
      float v = rmax[r];
      v = fmaxf(v, __shfl_xor(v, 1));
      v = fmaxf(v, __shfl_xor(v, 2));
      v = fmaxf(v, __shfl_xor(v, 4));
      v = fmaxf(v, __shfl_xor(v, 8));
      rmax[r] = v;
    }
    if (m0 == 0) {
      int row = bm * BM + wr * 64 + mi * 16 + q * 4;
#pragma unroll
      for (int r = 0; r < 4; r++)
        atomicMax(&rowmax[row + r], f2key(rmax[r]));
    }
  }
}

// =====================================================================
// Kernel T1: tail part 1 (unchanged).
// =====================================================================
__global__ __launch_bounds__(256) void tail1_kernel(
    const float* __restrict__ h1, const float* __restrict__ aw2,
    const unsigned* __restrict__ rowmax, const float* __restrict__ qinv,
    const float* __restrict__ hw1, const float* __restrict__ hb1,
    const float* __restrict__ hg2, const float* __restrict__ hbe2,
    float* __restrict__ favg, float* __restrict__ h1m,
    float* __restrict__ amean) {
  __shared__ __attribute__((aligned(16))) float S[12800];  // 51.2 KB
  const int blk = blockIdx.x;
  const int tid = threadIdx.x;
  const int wave = tid >> 6, lane = tid & 63;

  if (blk < 10) {
    const int d0 = blk * 64;
#pragma unroll
    for (int i = 0; i < 10; i++) S[i * 256 + tid] = h1[i * 256 + tid];
#pragma unroll
    for (int c = 0; c < 10; c++) {
      int e = c * 256 + tid;
      int row = e >> 4, col16 = e & 15;
      gl_lds16((const char*)aw2 + (size_t)row * D_DIM * 4 + d0 * 4 + col16 * 16,
               (char*)&S[2560] + e * 16);
    }
    __syncthreads();

    const int d = tid & 63, kg = tid >> 6;
    float a0 = 0.f, a1 = 0.f, a2 = 0.f, a3 = 0.f;
#pragma unroll 8
    for (int j = 0; j < 160; j++) {
      float w = S[2560 + j * 64 + d];
      a0 += S[(kg * 4 + 0) * 160 + j] * w;
      a1 += S[(kg * 4 + 1) * 160 + j] * w;
      a2 += S[(kg * 4 + 2) * 160 + j] * w;
      a3 += S[(kg * 4 + 3) * 160 + j] * w;
    }
    float p = fmaxf(a0, 0.f) + fmaxf(a1, 0.f) + fmaxf(a2, 0.f) + fmaxf(a3, 0.f);
    __syncthreads();
    S[kg * 64 + d] = p;
    __syncthreads();
    if (kg == 0)
      favg[d0 + d] = (S[d] + S[64 + d] + S[128 + d] + S[192 + d]) * (1.f / 16.f);
    return;
  }

  const int bO = (blk - 10) * 8;
  for (int e = tid; e < 8 * P_DIM; e += 256) {
    int row = bO * P_DIM + e;
    float mx = key2f(rowmax[row]);
    S[e] = 0.5f * (1.f - mx * qinv[row]);
  }
  __syncthreads();

#pragma unroll
  for (int i = 0; i < 2; i++) {
    int b = wave * 2 + i;
    float s = S[b * P_DIM + lane];
    s += S[b * P_DIM + lane + 64];
    s += S[b * P_DIM + lane + 128];
    if (lane < 33) s += S[b * P_DIM + lane + 192];
#pragma unroll
    for (int off = 32; off > 0; off >>= 1) s += __shfl_xor(s, off);
    if (lane == 0) amean[bO + b] = s * (1.f / 225.f);
  }

  const int j = tid & 127, bh = tid >> 7;
  float acc[4];
#pragma unroll
  for (int bb = 0; bb < 4; bb++) acc[bb] = hb1[j];

  for (int t = 0; t < 7; t++) {
    int p0 = t * 32;
#pragma unroll
    for (int c = 0; c < 4; c++) {
      int e = c * 256 + tid;
      int row = e >> 5, col16 = e & 31;
      gl_lds16((const char*)hw1 + (size_t)(p0 + row) * 128 * 4 + col16 * 16,
               (char*)&S[1800] + e * 16);
    }
    __syncthreads();
#pragma unroll 4
    for (int pr = 0; pr < 32; pr++) {
      float w = S[1800 + pr * 128 + j];
#pragma unroll
      for (int bb = 0; bb < 4; bb++)
        acc[bb] += S[(bh * 4 + bb) * P_DIM + p0 + pr] * w;
    }
    __syncthreads();
  }
  {
    float w = hw1[224 * 128 + j];
#pragma unroll
    for (int bb = 0; bb < 4; bb++)
      acc[bb] += S[(bh * 4 + bb) * P_DIM + 224] * w;
  }
#pragma unroll
  for (int bb = 0; bb < 4; bb++) {
    float h = fmaxf(acc[bb], 0.f) * hg2[j] + hbe2[j];
    h1m[(bO + bh * 4 + bb) * 128 + j] = h;
  }
}

// =====================================================================
// Kernel T2: tail part 2 (unchanged).
// =====================================================================
__global__ __launch_bounds__(256) void tail2_kernel(
    const float* __restrict__ q_img, const float* __restrict__ favg,
    const float* __restrict__ h1m, const float* __restrict__ amean,
    const float* __restrict__ hw2, const float* __restrict__ hb2,
    const float* __restrict__ hg3, const float* __restrict__ hbe3,
    const float* __restrict__ hw3, const float* __restrict__ hb3,
    const float* __restrict__ rw1, const float* __restrict__ rb1,
    const float* __restrict__ rg2, const float* __restrict__ rbe2,
    const float* __restrict__ rw2, const float* __restrict__ rb2,
    const float* __restrict__ rg3, const float* __restrict__ rbe3,
    const float* __restrict__ rw3, const float* __restrict__ rb3,
    float* __restrict__ out) {
  __shared__ __attribute__((aligned(16))) float S[14336];  // 57.3 KB
  const int tid = threadIdx.x;
  const int wave = tid >> 6, lane = tid & 63;
  const int bO = blockIdx.x * 8;

#pragma unroll
  for (int i = 0; i < 20; i++) {
    int e = i * 256 + tid;
    int d = e % D_DIM;
    S[e] = q_img[bO * D_DIM + e] - favg[d];
  }

#pragma unroll
  for (int c = 0; c < 4; c++) {
    int e = c * 256 + tid;
    int row = e >> 5, col16 = e & 31;
    gl_lds16((const char*)rw1 + (size_t)row * 128 * 4 + col16 * 16,
             (char*)&S[5120] + e * 16);
  }
  __syncthreads();

  const int j = tid & 127, bh = tid >> 7;
  float acc[4];
#pragma unroll
  for (int bb = 0; bb < 4; bb++) acc[bb] = rb1[j];

  for (int t = 0; t < 20; t++) {
    int bufC = 5120 + (t & 1) * 4096;
    int bufN = 5120 + ((t + 1) & 1) * 4096;
    if (t < 19) {
      int d0n = (t + 1) * 32;
#pragma unroll
      for (int c = 0; c < 4; c++) {
        int e = c * 256 + tid;
        int row = e >> 5, col16 = e & 31;
        gl_lds16((const char*)rw1 + (size_t)(d0n + row) * 128 * 4 + col16 * 16,
                 (char*)&S[bufN] + e * 16);
      }
    }
    int d0 = t * 32;
#pragma unroll 4
    for (int dr = 0; dr < 32; dr++) {
      float w = S[bufC + dr * 128 + j];
#pragma unroll
      for (int bb = 0; bb < 4; bb++)
        acc[bb] += S[(bh * 4 + bb) * D_DIM + d0 + dr] * w;
    }
    __syncthreads();
  }

#pragma unroll
  for (int bb = 0; bb < 4; bb++) {
    float h = fmaxf(acc[bb], 0.f) * rg2[j] + rbe2[j];
    S[13312 + (bh * 4 + bb) * 128 + j] = h;
  }
  __syncthreads();

#pragma unroll
  for (int c = 0; c < 8; c++) {
    int e = c * 256 + tid;
    gl_lds16((const char*)rw2 + e * 16, (char*)&S[0] + e * 16);
  }
#pragma unroll
  for (int i = 0; i < 4; i++) {
    int e = i * 256 + tid;
    S[8192 + e] = h1m[bO * 128 + e];
  }
  __syncthreads();

  {
    const int n = tid & 63, bg = tid >> 6;
#pragma unroll
    for (int bb = 0; bb < 2; bb++) {
      int b = bg * 2 + bb;
      float a = rb2[n];
#pragma unroll 8
      for (int jj = 0; jj < 128; jj++) a += S[13312 + b * 128 + jj] * S[jj * 64 + n];
      S[10240 + b * 64 + n] = fmaxf(a, 0.f) * rg3[n] + rbe3[n];
    }
  }
  __syncthreads();

#pragma unroll
  for (int c = 0; c < 8; c++) {
    int e = c * 256 + tid;
    gl_lds16((const char*)hw2 + e * 16, (char*)&S[0] + e * 16);
  }

#pragma unroll
  for (int i = 0; i < 2; i++) {
    int b = wave * 2 + i;
    float v = S[10240 + b * 64 + lane] * rw3[lane];
#pragma unroll
    for (int off = 32; off > 0; off >>= 1) v += __shfl_xor(v, off);
    if (lane == 0) S[11264 + b] = sigmoidf(v + rb3[0]);
  }
  __syncthreads();

  {
    const int n = tid & 63, bg = tid >> 6;
#pragma unroll
    for (int bb = 0; bb < 2; bb++) {
      int b = bg * 2 + bb;
      float a = hb2[n];
#pragma unroll 8
      for (int jj = 0; jj < 128; jj++) a += S[8192 + b * 128 + jj] * S[jj * 64 + n];
      S[10752 + b * 64 + n] = fmaxf(a, 0.f) * hg3[n] + hbe3[n];
    }
  }
  __syncthreads();

#pragma unroll
  for (int i = 0; i < 2; i++) {
    int b = wave * 2 + i;
    float v = S[10752 + b * 64 + lane] * hw3[lane];
#pragma unroll
    for (int off = 32; off > 0; off >>= 1) v += __shfl_xor(v, off);
    if (lane == 0) S[11272 + b] = sigmoidf(v + hb3[0]);
  }
  __syncthreads();

  if (tid < 8) {
    int b = bO + tid;
    out[b] = 0.5f * (S[11264 + tid] + S[11272 + tid]) + amean[b];
  }
}

// ---------------- launch ----------------
extern "C" void kernel_launch(void* const* d_in, const int* in_sizes, int n_in,
                              void* d_out, int out_size, void* d_ws, size_t ws_size,
                              hipStream_t stream) {
  const float* q_patch = (const float*)d_in[0];
  const float* r_patch = (const float*)d_in[1];
  const float* q_img   = (const float*)d_in[2];
  const float* r_img   = (const float*)d_in[3];
  const float* adpt_w1 = (const float*)d_in[4];
  const float* adpt_w2 = (const float*)d_in[5];
  const float* dh_w1 = (const float*)d_in[6];
  const float* dh_b1 = (const float*)d_in[7];
  const float* dh_g2 = (const float*)d_in[8];
  const float* dh_be2 = (const float*)d_in[9];
  const float* dh_w2 = (const float*)d_in[10];
  const float* dh_b2 = (const float*)d_in[11];
  const float* dh_g3 = (const float*)d_in[12];
  const float* dh_be3 = (const float*)d_in[13];
  const float* dh_w3 = (const float*)d_in[14];
  const float* dh_b3 = (const float*)d_in[15];
  const float* dr_w1 = (const float*)d_in[16];
  const float* dr_b1 = (const float*)d_in[17];
  const float* dr_g2 = (const float*)d_in[18];
  const float* dr_be2 = (const float*)d_in[19];
  const float* dr_w2 = (const float*)d_in[20];
  const float* dr_b2 = (const float*)d_in[21];
  const float* dr_g3 = (const float*)d_in[22];
  const float* dr_be3 = (const float*)d_in[23];
  const float* dr_w3 = (const float*)d_in[24];
  const float* dr_b3 = (const float*)d_in[25];

  // ws layout (bytes) — fp8 staging buffers
  const size_t QB_BYTES = (size_t)MPAD * D_DIM;   // 9,338,880
  const size_t RB_BYTES = (size_t)NPAD * D_DIM;   // 2,457,600
  char* ws = (char*)d_ws;
  unsigned char* qb = (unsigned char*)(ws);
  unsigned char* rb = (unsigned char*)(ws + QB_BYTES);
  float* qinv        = (float*)(ws + QB_BYTES + RB_BYTES);
  unsigned* rowmax   = (unsigned*)(ws + QB_BYTES + RB_BYTES + (size_t)M_REAL * 4);
  float* h1          = (float*)(ws + QB_BYTES + RB_BYTES + (size_t)M_REAL * 4 + (size_t)MPAD * 4);
  float* favg        = h1 + 16 * 160;
  float* h1m         = favg + D_DIM;
  float* amean       = h1m + 64 * 128;

  stage_all_kernel<<<ABLKS + QBLKS + RBLKS, 256, 0, stream>>>(
      q_patch, r_patch, r_img, adpt_w1, qb, rb, qinv, rowmax, h1);
  sim_max_kernel<<<8 * MC * NTILES, 1024, 0, stream>>>(qb, rb, rowmax);
  tail1_kernel<<<18, 256, 0, stream>>>(
      h1, adpt_w2, rowmax, qinv, dh_w1, dh_b1, dh_g2, dh_be2,
      favg, h1m, amean);
  tail2_kernel<<<8, 256, 0, stream>>>(
      q_img, favg, h1m, amean,
      dh_w2, dh_b2, dh_g3, dh_be3, dh_w3, dh_b3,
      dr_w1, dr_b1, dr_g2, dr_be2, dr_w2, dr_b2, dr_g3, dr_be3, dr_w3, dr_b3,
      (float*)d_out);
}

// Round 7
// 297.995 us; speedup vs baseline: 1.3805x; 1.1145x over previous
//
#include <hip/hip_runtime.h>
#include <stdint.h>

// ---------------- problem dims ----------------
#define B_DIM 64
#define P_DIM 225
#define K_DIM 16
#define D_DIM 640
#define M_REAL (B_DIM * P_DIM)   // 14400 query rows
#define N_REAL (K_DIM * P_DIM)   // 3600 reference rows

// ---------------- GEMM tiling (round-2 proven config) ----------------
#define BM 128
#define BN 128
#define MTILES 113               // ceil(14400/128) -> Mpad 14464
#define NTILES 29                // ceil(3600/128)  -> Npad 3712
#define MPAD (MTILES * BM)
#define NPAD (NTILES * BN)
#define MCHUNK 15                // ceil(MTILES/8) per-XCD bm groups

typedef float f32x4 __attribute__((ext_vector_type(4)));
typedef int   i32x4 __attribute__((ext_vector_type(4)));
typedef int   i32x8 __attribute__((ext_vector_type(8)));

// ---------------- helpers ----------------
// float -> OCP e4m3 byte (v_cvt_pk_fp8_f32)
__device__ __forceinline__ unsigned char f2fp8(float f) {
  int r = __builtin_amdgcn_cvt_pk_fp8_f32(f, f, 0, false);
  return (unsigned char)(r & 0xFF);
}

// monotone float -> uint key (order-preserving), for atomicMax on floats
__device__ __forceinline__ unsigned f2key(float f) {
  union { float f; unsigned u; } v; v.f = f;
  unsigned u = v.u;
  return (u & 0x80000000u) ? ~u : (u | 0x80000000u);
}
__device__ __forceinline__ float key2f(unsigned k) {
  unsigned b = (k & 0x80000000u) ? (k ^ 0x80000000u) : ~k;
  union { unsigned u; float f; } v; v.u = b;
  return v.f;
}

__device__ __forceinline__ void gl_lds16(const void* g, void* l) {
  __builtin_amdgcn_global_load_lds(
      (const __attribute__((address_space(1))) void*)g,
      (__attribute__((address_space(3))) void*)l,
      16, 0, 0);
}

__device__ __forceinline__ float sigmoidf(float x) {
  return 1.f / (1.f + expf(-x));
}

// =====================================================================
// Kernel A: staging (fp8 e4m3) + FULL adapter->favg in one extra block.
//   blk 0       : adapter: h1 = relu(r_img@aw1); favg = mean_k relu(h1@aw2)
//                 (runs concurrently with the ~4.5K staging blocks)
//   blk 1..Q    : q rows -> qb (fp8) + qinv + rowmax init
//   blk Q+1..   : r rows -> rb (fp8, norm x16)
// =====================================================================
#define QBLKS (MPAD / 4)
#define RBLKS (NPAD / 4)
__global__ __launch_bounds__(256) void stage_all_kernel(
    const float* __restrict__ q, const float* __restrict__ r,
    const float* __restrict__ r_img, const float* __restrict__ aw1,
    const float* __restrict__ aw2,
    unsigned char* __restrict__ qb, unsigned char* __restrict__ rb,
    float* __restrict__ qinv, unsigned* __restrict__ rowmax,
    float* __restrict__ favg) {
  const int blk = blockIdx.x;
  const int tid = threadIdx.x;

  if (blk == 0) {
    // S: [0..10239] = r_img (16x640), [10240..12799] = h1 (16x160)
    __shared__ float S[12800];  // 51.2 KB
    for (int i = tid; i < 16 * D_DIM; i += 256) S[i] = r_img[i];
    __syncthreads();
    if (tid < 160) {
      float a[16];
#pragma unroll
      for (int k = 0; k < 16; k++) a[k] = 0.f;
#pragma unroll 4
      for (int d = 0; d < D_DIM; d++) {
        float w = aw1[d * 160 + tid];
#pragma unroll
        for (int k = 0; k < 16; k++) a[k] += S[k * D_DIM + d] * w;
      }
#pragma unroll
      for (int k = 0; k < 16; k++) S[10240 + k * 160 + tid] = fmaxf(a[k], 0.f);
    }
    __syncthreads();
#pragma unroll
    for (int rep = 0; rep < 3; rep++) {
      int d = rep * 256 + tid;
      if (d < D_DIM) {
        float a[16];
#pragma unroll
        for (int k = 0; k < 16; k++) a[k] = 0.f;
#pragma unroll 4
        for (int j = 0; j < 160; j++) {
          float w = aw2[j * D_DIM + d];
#pragma unroll
          for (int k = 0; k < 16; k++) a[k] += S[10240 + k * 160 + j] * w;
        }
        float s = 0.f;
#pragma unroll
        for (int k = 0; k < 16; k++) s += fmaxf(a[k], 0.f);
        favg[d] = s * (1.f / 16.f);
      }
    }
    return;
  }

  if (blk <= QBLKS) {
    int row = (blk - 1) * 4 + (tid >> 6);
    int lane = tid & 63;
    if (lane == 0) rowmax[row] = 0u;
    unsigned char* dst = qb + (long)row * D_DIM;
    if (row >= M_REAL) {
#pragma unroll
      for (int i = 0; i < 10; i++) dst[i * 64 + lane] = 0;
      return;
    }
    const float* src = q + (long)row * D_DIM;
    float v[10];
    float ss = 0.f;
#pragma unroll
    for (int i = 0; i < 10; i++) { v[i] = src[i * 64 + lane]; ss += v[i] * v[i]; }
#pragma unroll
    for (int off = 32; off > 0; off >>= 1) ss += __shfl_xor(ss, off);
    float inv = 1.f / (sqrtf(ss) + 1e-6f);
    if (lane == 0) qinv[row] = inv * (1.f / 16.f);  // fold r-scale
#pragma unroll
    for (int i = 0; i < 10; i++) dst[i * 64 + lane] = f2fp8(v[i]);
    return;
  }

  {
    int row = (blk - 1 - QBLKS) * 4 + (tid >> 6);
    int lane = tid & 63;
    unsigned char* dst = rb + (long)row * D_DIM;
    if (row >= N_REAL) {
#pragma unroll
      for (int i = 0; i < 10; i++) dst[i * 64 + lane] = 0;
      return;
    }
    const float* src = r + (long)row * D_DIM;
    float v[10];
    float ss = 0.f;
#pragma unroll
    for (int i = 0; i < 10; i++) { v[i] = src[i * 64 + lane]; ss += v[i] * v[i]; }
#pragma unroll
    for (int off = 32; off > 0; off >>= 1) ss += __shfl_xor(ss, off);
    float sc = 16.f / (sqrtf(ss) + 1e-6f);   // normalize, x16 into e4m3 normals
#pragma unroll
    for (int i = 0; i < 10; i++) dst[i * 64 + lane] = f2fp8(v[i] * sc);
  }
}

// =====================================================================
// Kernel B: fused MX-fp8 MFMA GEMM + row-max — ROUND-2 VERSION VERBATIM
//   (measured 59.3 us, 88 VGPR, no spill, FETCH 13.9 MB).
//   The 256^2 8-phase family (rounds 3-5) is structurally spill-bound
//   on this compiler (caps VGPR at 128/64 for 8/16-wave blocks).
// =====================================================================
__global__ __launch_bounds__(256) void sim_max_kernel(
    const unsigned char* __restrict__ Qb,
    const unsigned char* __restrict__ Rb,
    unsigned* __restrict__ rowmax) {
  __shared__ __attribute__((aligned(16))) unsigned char As[2][BM * 128];  // 2x16 KB
  __shared__ __attribute__((aligned(16))) unsigned char Bs[2][BN * 128];  // 2x16 KB

  const int xcd = blockIdx.x & 7;
  const int idx = blockIdx.x >> 3;
  const int bm = xcd + 8 * (idx % MCHUNK);
  const int bn = idx / MCHUNK;
  if (bm >= MTILES) return;

  const int tid = threadIdx.x;
  const int wave = tid >> 6, lane = tid & 63;
  const int wr = wave >> 1, wc = wave & 1;
  const int q = lane >> 4, m0 = lane & 15;   // k-chunk (32B) / frag row

  // ---- staging geometry (pre-swizzled global source, linear LDS dest) ----
  const int sRow = tid >> 3;        // row offset within the 32-row round
  const int sp = tid & 7;           // phys chunk
  const int sSrcC = (sp ^ (sRow & 7)) << 4;  // source byte within 128B slice
  const int sLds = tid * 16;

  // ---- frag read offsets ----
  const int r7 = m0 & 7;
  const int cLo = (((q << 1) | 0) ^ r7) << 4;
  const int cHi = (((q << 1) | 1) ^ r7) << 4;

  const int aBase = bm * BM;
  const int bBase = bn * BN;

  f32x4 zero = {0.f, 0.f, 0.f, 0.f};
  f32x4 acc[4][4];
#pragma unroll
  for (int i = 0; i < 4; i++)
#pragma unroll
    for (int j = 0; j < 4; j++) acc[i][j] = zero;

  union frag_u { i32x8 v; i32x4 h[2]; };

#define STAGE_KT(KT, BUF)                                                     \
  {                                                                           \
    const int k0_ = (KT) * 128;                                               \
    _Pragma("unroll")                                                         \
    for (int rd = 0; rd < 4; rd++) {                                          \
      const int row_ = rd * 32 + sRow;                                        \
      gl_lds16(Qb + (size_t)(aBase + row_) * D_DIM + k0_ + sSrcC,             \
               &As[BUF][rd * 4096 + sLds]);                                   \
      gl_lds16(Rb + (size_t)(bBase + row_) * D_DIM + k0_ + sSrcC,             \
               &Bs[BUF][rd * 4096 + sLds]);                                   \
    }                                                                         \
  }

  // prologue: stage tile 0
  STAGE_KT(0, 0);
  __syncthreads();

#pragma unroll
  for (int kt = 0; kt < 5; kt++) {
    const int cur = kt & 1;
    // issue-early prefetch of next K-tile into the other buffer
    if (kt < 4) STAGE_KT(kt + 1, cur ^ 1);

    frag_u af[4], bf[4];
#pragma unroll
    for (int mi = 0; mi < 4; mi++) {
      const int rb_ = (wr * 64 + mi * 16 + m0) * 128;
      af[mi].h[0] = *(const i32x4*)&As[cur][rb_ + cLo];
      af[mi].h[1] = *(const i32x4*)&As[cur][rb_ + cHi];
    }
#pragma unroll
    for (int ni = 0; ni < 4; ni++) {
      const int rb_ = (wc * 64 + ni * 16 + m0) * 128;
      bf[ni].h[0] = *(const i32x4*)&Bs[cur][rb_ + cLo];
      bf[ni].h[1] = *(const i32x4*)&Bs[cur][rb_ + cHi];
    }

    __builtin_amdgcn_s_setprio(1);
#pragma unroll
    for (int mi = 0; mi < 4; mi++)
#pragma unroll
      for (int ni = 0; ni < 4; ni++)
        acc[mi][ni] = __builtin_amdgcn_mfma_scale_f32_16x16x128_f8f6f4(
            af[mi].v, bf[ni].v, acc[mi][ni],
            0 /*cbsz: A=fp8 e4m3*/, 0 /*blgp: B=fp8 e4m3*/,
            0, 0x7F7F7F7Fu /*scale A = 1.0*/,
            0, 0x7F7F7F7Fu /*scale B = 1.0*/);
    __builtin_amdgcn_s_setprio(0);

    if (kt < 4) __syncthreads();
  }
#undef STAGE_KT

  // epilogue: per-row max over this block's 128 columns, then global atomicMax
  const int colBase = bn * BN + wc * 64;
#pragma unroll
  for (int mi = 0; mi < 4; mi++) {
    float rmax[4] = {-3.0e38f, -3.0e38f, -3.0e38f, -3.0e38f};
#pragma unroll
    for (int ni = 0; ni < 4; ni++) {
      bool valid = (colBase + ni * 16 + m0) < N_REAL;
#pragma unroll
      for (int r = 0; r < 4; r++) {
        float v = valid ? acc[mi][ni][r] : -3.0e38f;
        rmax[r] = fmaxf(rmax[r], v);
      }
    }
#pragma unroll
    for (int r = 0; r < 4; r++) {
      float v = rmax[r];
      v = fmaxf(v, __shfl_xor(v, 1));
      v = fmaxf(v, __shfl_xor(v, 2));
      v = fmaxf(v, __shfl_xor(v, 4));
      v = fmaxf(v, __shfl_xor(v, 8));
      rmax[r] = v;
    }
    if (m0 == 0) {
      int row = bm * BM + wr * 64 + mi * 16 + q * 4;
#pragma unroll
      for (int r = 0; r < 4; r++)
        atomicMax(&rowmax[row + r], f2key(rmax[r]));
    }
  }
}

// =====================================================================
// Kernel C: fused tail — ONE kernel, 64 blocks (1 batch row each).
//   Replaces tail1+tail2 (18+8 small-grid latency-bound launches).
//   Per block: amap row -> amean; s_map head (225->128->64->1);
//   res = q_img - favg; s_ref head (640->128->64->1); combine.
//   GEMV1s split the reduction across thread-halves (bh) -> LDS combine.
// =====================================================================
__global__ __launch_bounds__(256) void tail_fused_kernel(
    const unsigned* __restrict__ rowmax, const float* __restrict__ qinv,
    const float* __restrict__ q_img, const float* __restrict__ favg,
    const float* __restrict__ hw1, const float* __restrict__ hb1,
    const float* __restrict__ hg2, const float* __restrict__ hbe2,
    const float* __restrict__ hw2, const float* __restrict__ hb2,
    const float* __restrict__ hg3, const float* __restrict__ hbe3,
    const float* __restrict__ hw3, const float* __restrict__ hb3,
    const float* __restrict__ rw1, const float* __restrict__ rb1,
    const float* __restrict__ rg2, const float* __restrict__ rbe2,
    const float* __restrict__ rw2, const float* __restrict__ rb2,
    const float* __restrict__ rg3, const float* __restrict__ rbe3,
    const float* __restrict__ rw3, const float* __restrict__ rb3,
    float* __restrict__ out) {
  __shared__ float A[240];    // amap row (225)
  __shared__ float R[640];    // res_img row
  __shared__ float P[256];    // GEMV1 partials
  __shared__ float Hr[128];   // ref hidden1 (post bn)
  __shared__ float Hm[128];   // map hidden1 (post bn)
  __shared__ float Q[256];    // layer2 partials (both heads)
  __shared__ float Hr2[64];   // ref hidden2
  __shared__ float Hm2[64];   // map hidden2
  __shared__ float red[16];   // [0..3] amean partials, [8]=s_ref, [9]=s_map

  const int b = blockIdx.x;
  const int tid = threadIdx.x;
  const int wave = tid >> 6, lane = tid & 63;

  // ---- amap row + amean partials; res row ----
  float am = 0.f;
  if (tid < P_DIM) {
    float mx = key2f(rowmax[b * P_DIM + tid]);
    float a = 0.5f * (1.f - mx * qinv[b * P_DIM + tid]);
    A[tid] = a;
    am = a;
  }
#pragma unroll
  for (int off = 32; off > 0; off >>= 1) am += __shfl_xor(am, off);
  if (lane == 0) red[wave] = am;
  for (int i = tid; i < D_DIM; i += 256) R[i] = q_img[b * D_DIM + i] - favg[i];
  __syncthreads();

  const int j = tid & 127, bh = tid >> 7;

  // ---- s_ref GEMV1: 640 -> 128 (halved over bh) ----
  {
    float acc = bh ? 0.f : rb1[j];
    const int d0 = bh * 320;
#pragma unroll 8
    for (int d = 0; d < 320; d++) acc += R[d0 + d] * rw1[(d0 + d) * 128 + j];
    P[bh * 128 + j] = acc;
  }
  __syncthreads();
  if (tid < 128) Hr[tid] = fmaxf(P[tid] + P[128 + tid], 0.f) * rg2[tid] + rbe2[tid];
  __syncthreads();

  // ---- s_map GEMV1: 225 -> 128 (split 128/97 over bh) ----
  {
    float acc = bh ? 0.f : hb1[j];
    const int p0 = bh * 128;
    const int pn = bh ? (P_DIM - 128) : 128;
#pragma unroll 8
    for (int p = 0; p < pn; p++) acc += A[p0 + p] * hw1[(p0 + p) * 128 + j];
    P[bh * 128 + j] = acc;
  }
  __syncthreads();
  if (tid < 128) Hm[tid] = fmaxf(P[tid] + P[128 + tid], 0.f) * hg2[tid] + hbe2[tid];
  __syncthreads();

  // ---- layer2 both heads: 128 -> 64; g0/g1 = ref halves, g2/g3 = map ----
  {
    const int n = tid & 63, g = tid >> 6;
    const float* h = (g < 2) ? Hr : Hm;
    const float* w = (g < 2) ? rw2 : hw2;
    float acc = (g == 0) ? rb2[n] : (g == 2) ? hb2[n] : 0.f;
    const int j0 = (g & 1) * 64;
#pragma unroll 8
    for (int jj = 0; jj < 64; jj++) acc += h[j0 + jj] * w[(j0 + jj) * 64 + n];
    Q[g * 64 + n] = acc;
  }
  __syncthreads();
  if (tid < 64) Hr2[tid] = fmaxf(Q[tid] + Q[64 + tid], 0.f) * rg3[tid] + rbe3[tid];
  else if (tid < 128) {
    int n = tid - 64;
    Hm2[n] = fmaxf(Q[128 + n] + Q[192 + n], 0.f) * hg3[n] + hbe3[n];
  }
  __syncthreads();

  // ---- layer3 + sigmoid: wave 0 = ref, wave 1 = map ----
  if (wave == 0) {
    float v = Hr2[lane] * rw3[lane];
#pragma unroll
    for (int off = 32; off > 0; off >>= 1) v += __shfl_xor(v, off);
    if (lane == 0) red[8] = sigmoidf(v + rb3[0]);
  } else if (wave == 1) {
    float v = Hm2[lane] * hw3[lane];
#pragma unroll
    for (int off = 32; off > 0; off >>= 1) v += __shfl_xor(v, off);
    if (lane == 0) red[9] = sigmoidf(v + hb3[0]);
  }
  __syncthreads();

  if (tid == 0) {
    float amean = (red[0] + red[1] + red[2] + red[3]) * (1.f / 225.f);
    out[b] = 0.5f * (red[8] + red[9]) + amean;
  }
}

// ---------------- launch ----------------
extern "C" void kernel_launch(void* const* d_in, const int* in_sizes, int n_in,
                              void* d_out, int out_size, void* d_ws, size_t ws_size,
                              hipStream_t stream) {
  const float* q_patch = (const float*)d_in[0];
  const float* r_patch = (const float*)d_in[1];
  const float* q_img   = (const float*)d_in[2];
  const float* r_img   = (const float*)d_in[3];
  const float* adpt_w1 = (const float*)d_in[4];
  const float* adpt_w2 = (const float*)d_in[5];
  const float* dh_w1 = (const float*)d_in[6];
  const float* dh_b1 = (const float*)d_in[7];
  const float* dh_g2 = (const float*)d_in[8];
  const float* dh_be2 = (const float*)d_in[9];
  const float* dh_w2 = (const float*)d_in[10];
  const float* dh_b2 = (const float*)d_in[11];
  const float* dh_g3 = (const float*)d_in[12];
  const float* dh_be3 = (const float*)d_in[13];
  const float* dh_w3 = (const float*)d_in[14];
  const float* dh_b3 = (const float*)d_in[15];
  const float* dr_w1 = (const float*)d_in[16];
  const float* dr_b1 = (const float*)d_in[17];
  const float* dr_g2 = (const float*)d_in[18];
  const float* dr_be2 = (const float*)d_in[19];
  const float* dr_w2 = (const float*)d_in[20];
  const float* dr_b2 = (const float*)d_in[21];
  const float* dr_g3 = (const float*)d_in[22];
  const float* dr_be3 = (const float*)d_in[23];
  const float* dr_w3 = (const float*)d_in[24];
  const float* dr_b3 = (const float*)d_in[25];

  // ws layout (bytes) — fp8 staging buffers
  const size_t QB_BYTES = (size_t)MPAD * D_DIM;   // 9,256,960
  const size_t RB_BYTES = (size_t)NPAD * D_DIM;   // 2,375,680
  char* ws = (char*)d_ws;
  unsigned char* qb = (unsigned char*)(ws);
  unsigned char* rb = (unsigned char*)(ws + QB_BYTES);
  float* qinv        = (float*)(ws + QB_BYTES + RB_BYTES);
  unsigned* rowmax   = (unsigned*)(ws + QB_BYTES + RB_BYTES + (size_t)M_REAL * 4);
  float* favg        = (float*)(ws + QB_BYTES + RB_BYTES + (size_t)M_REAL * 4 + (size_t)MPAD * 4);

  stage_all_kernel<<<1 + QBLKS + RBLKS, 256, 0, stream>>>(
      q_patch, r_patch, r_img, adpt_w1, adpt_w2, qb, rb, qinv, rowmax, favg);
  sim_max_kernel<<<8 * MCHUNK * NTILES, 256, 0, stream>>>(qb, rb, rowmax);
  tail_fused_kernel<<<B_DIM, 256, 0, stream>>>(
      rowmax, qinv, q_img, favg,
      dh_w1, dh_b1, dh_g2, dh_be2, dh_w2, dh_b2, dh_g3, dh_be3, dh_w3, dh_b3,
      dr_w1, dr_b1, dr_g2, dr_be2, dr_w2, dr_b2, dr_g3, dr_be3, dr_w3, dr_b3,
      (float*)d_out);
}

// Round 8
// 249.955 us; speedup vs baseline: 1.6459x; 1.1922x over previous
//
#include <hip/hip_runtime.h>
#include <stdint.h>

// ---------------- problem dims ----------------
#define B_DIM 64
#define P_DIM 225
#define K_DIM 16
#define D_DIM 640
#define M_REAL (B_DIM * P_DIM)   // 14400 query rows
#define N_REAL (K_DIM * P_DIM)   // 3600 reference rows

// ---------------- GEMM tiling (round-2 proven config) ----------------
#define BM 128
#define BN 128
#define MTILES 113               // ceil(14400/128) -> Mpad 14464
#define NTILES 29                // ceil(3600/128)  -> Npad 3712
#define MPAD (MTILES * BM)
#define NPAD (NTILES * BN)
#define MCHUNK 15                // ceil(MTILES/8) per-XCD bm groups

typedef float f32x4 __attribute__((ext_vector_type(4)));
typedef int   i32x4 __attribute__((ext_vector_type(4)));
typedef int   i32x8 __attribute__((ext_vector_type(8)));

// ---------------- helpers ----------------
// monotone float -> uint key (order-preserving), for atomicMax on floats
__device__ __forceinline__ unsigned f2key(float f) {
  union { float f; unsigned u; } v; v.f = f;
  unsigned u = v.u;
  return (u & 0x80000000u) ? ~u : (u | 0x80000000u);
}
__device__ __forceinline__ float key2f(unsigned k) {
  unsigned b = (k & 0x80000000u) ? (k ^ 0x80000000u) : ~k;
  union { unsigned u; float f; } v; v.u = b;
  return v.f;
}

__device__ __forceinline__ void gl_lds16(const void* g, void* l) {
  __builtin_amdgcn_global_load_lds(
      (const __attribute__((address_space(1))) void*)g,
      (__attribute__((address_space(3))) void*)l,
      16, 0, 0);
}

__device__ __forceinline__ float sigmoidf(float x) {
  return 1.f / (1.f + expf(-x));
}

// pack 4 floats -> 4 fp8 e4m3 bytes in one dword
__device__ __forceinline__ unsigned pk_fp8x4(float a, float b, float c, float d) {
  int w = __builtin_amdgcn_cvt_pk_fp8_f32(a, b, 0, false);   // bytes 0,1
  w = __builtin_amdgcn_cvt_pk_fp8_f32(c, d, w, true);        // bytes 2,3
  return (unsigned)w;
}

// =====================================================================
// Kernel A: staging (fp8 e4m3) + adapter spread over 16 parallel blocks.
//   blk 0..15   : adapter for one k: h1[k]=relu(r_img[k]@aw1) (LDS),
//                 fa[k][:]=relu(h1[k]@aw2) -> global (mean moves to tail).
//                 LDS only 3.2 KB (round-7's 51.2 KB S[] killed occupancy).
//   blk 16..    : q rows -> qb fp8 (16 rows/block, float4 loads,
//                 cvt_pk packing, dword stores) + qinv + rowmax init
//   then        : r rows -> rb fp8 (norm x16)
// =====================================================================
#define ABLKS 16
#define QBLKS (MPAD / 16)        // 904
#define RBLKS (NPAD / 16)        // 232
__global__ __launch_bounds__(256) void stage_all_kernel(
    const float* __restrict__ q, const float* __restrict__ r,
    const float* __restrict__ r_img, const float* __restrict__ aw1,
    const float* __restrict__ aw2,
    unsigned char* __restrict__ qb, unsigned char* __restrict__ rb,
    float* __restrict__ qinv, unsigned* __restrict__ rowmax,
    float* __restrict__ fa) {
  const int blk = blockIdx.x;
  const int tid = threadIdx.x;

  if (blk < ABLKS) {
    __shared__ float Rk[D_DIM];   // 2.56 KB
    __shared__ float H[160];      // 0.64 KB
    const int k = blk;
#pragma unroll
    for (int rep = 0; rep < 3; rep++) {
      int d = rep * 256 + tid;
      if (d < D_DIM) Rk[d] = r_img[k * D_DIM + d];
    }
    __syncthreads();
    if (tid < 160) {
      float a = 0.f;
#pragma unroll 8
      for (int d = 0; d < D_DIM; d++) a += Rk[d] * aw1[d * 160 + tid];
      H[tid] = fmaxf(a, 0.f);
    }
    __syncthreads();
#pragma unroll
    for (int rep = 0; rep < 3; rep++) {
      int d = rep * 256 + tid;
      if (d < D_DIM) {
        float a = 0.f;
#pragma unroll 8
        for (int j = 0; j < 160; j++) a += H[j] * aw2[j * D_DIM + d];
        fa[k * D_DIM + d] = fmaxf(a, 0.f);
      }
    }
    return;
  }

  // ---- staging: 16 rows per block, 16 threads per row ----
  const int g = tid >> 4;          // row group 0..15
  const int t = tid & 15;          // thread within row

  if (blk < ABLKS + QBLKS) {
    const int row = (blk - ABLKS) * 16 + g;
    if (t == 0) rowmax[row] = 0u;
    unsigned* dstw = (unsigned*)(qb + (long)row * D_DIM);
    if (row >= M_REAL) {
#pragma unroll
      for (int i = 0; i < 10; i++) dstw[i * 16 + t] = 0u;
      return;
    }
    const float4* src = (const float4*)(q + (long)row * D_DIM);
    float4 v[10];
    float ss = 0.f;
#pragma unroll
    for (int i = 0; i < 10; i++) {
      v[i] = src[i * 16 + t];
      ss += v[i].x * v[i].x + v[i].y * v[i].y + v[i].z * v[i].z + v[i].w * v[i].w;
    }
    ss += __shfl_xor(ss, 1); ss += __shfl_xor(ss, 2);
    ss += __shfl_xor(ss, 4); ss += __shfl_xor(ss, 8);
    float inv = 1.f / (sqrtf(ss) + 1e-6f);
    if (t == 0) qinv[row] = inv * (1.f / 16.f);  // fold r-scale
#pragma unroll
    for (int i = 0; i < 10; i++)
      dstw[i * 16 + t] = pk_fp8x4(v[i].x, v[i].y, v[i].z, v[i].w);
    return;
  }

  {
    const int row = (blk - ABLKS - QBLKS) * 16 + g;
    unsigned* dstw = (unsigned*)(rb + (long)row * D_DIM);
    if (row >= N_REAL) {
#pragma unroll
      for (int i = 0; i < 10; i++) dstw[i * 16 + t] = 0u;
      return;
    }
    const float4* src = (const float4*)(r + (long)row * D_DIM);
    float4 v[10];
    float ss = 0.f;
#pragma unroll
    for (int i = 0; i < 10; i++) {
      v[i] = src[i * 16 + t];
      ss += v[i].x * v[i].x + v[i].y * v[i].y + v[i].z * v[i].z + v[i].w * v[i].w;
    }
    ss += __shfl_xor(ss, 1); ss += __shfl_xor(ss, 2);
    ss += __shfl_xor(ss, 4); ss += __shfl_xor(ss, 8);
    float sc = 16.f / (sqrtf(ss) + 1e-6f);   // normalize, x16 into e4m3 normals
#pragma unroll
    for (int i = 0; i < 10; i++)
      dstw[i * 16 + t] = pk_fp8x4(v[i].x * sc, v[i].y * sc, v[i].z * sc, v[i].w * sc);
  }
}

// =====================================================================
// Kernel B: fused MX-fp8 MFMA GEMM + row-max — ROUND-2 VERSION VERBATIM
//   (measured 59.3 us, 88 VGPR, no spill, FETCH 13.9 MB).
// =====================================================================
__global__ __launch_bounds__(256) void sim_max_kernel(
    const unsigned char* __restrict__ Qb,
    const unsigned char* __restrict__ Rb,
    unsigned* __restrict__ rowmax) {
  __shared__ __attribute__((aligned(16))) unsigned char As[2][BM * 128];  // 2x16 KB
  __shared__ __attribute__((aligned(16))) unsigned char Bs[2][BN * 128];  // 2x16 KB

  const int xcd = blockIdx.x & 7;
  const int idx = blockIdx.x >> 3;
  const int bm = xcd + 8 * (idx % MCHUNK);
  const int bn = idx / MCHUNK;
  if (bm >= MTILES) return;

  const int tid = threadIdx.x;
  const int wave = tid >> 6, lane = tid & 63;
  const int wr = wave >> 1, wc = wave & 1;
  const int q = lane >> 4, m0 = lane & 15;   // k-chunk (32B) / frag row

  // ---- staging geometry (pre-swizzled global source, linear LDS dest) ----
  const int sRow = tid >> 3;        // row offset within the 32-row round
  const int sp = tid & 7;           // phys chunk
  const int sSrcC = (sp ^ (sRow & 7)) << 4;  // source byte within 128B slice
  const int sLds = tid * 16;

  // ---- frag read offsets ----
  const int r7 = m0 & 7;
  const int cLo = (((q << 1) | 0) ^ r7) << 4;
  const int cHi = (((q << 1) | 1) ^ r7) << 4;

  const int aBase = bm * BM;
  const int bBase = bn * BN;

  f32x4 zero = {0.f, 0.f, 0.f, 0.f};
  f32x4 acc[4][4];
#pragma unroll
  for (int i = 0; i < 4; i++)
#pragma unroll
    for (int j = 0; j < 4; j++) acc[i][j] = zero;

  union frag_u { i32x8 v; i32x4 h[2]; };

#define STAGE_KT(KT, BUF)                                                     \
  {                                                                           \
    const int k0_ = (KT) * 128;                                               \
    _Pragma("unroll")                                                         \
    for (int rd = 0; rd < 4; rd++) {                                          \
      const int row_ = rd * 32 + sRow;                                        \
      gl_lds16(Qb + (size_t)(aBase + row_) * D_DIM + k0_ + sSrcC,             \
               &As[BUF][rd * 4096 + sLds]);                                   \
      gl_lds16(Rb + (size_t)(bBase + row_) * D_DIM + k0_ + sSrcC,             \
               &Bs[BUF][rd * 4096 + sLds]);                                   \
    }                                                                         \
  }

  // prologue: stage tile 0
  STAGE_KT(0, 0);
  __syncthreads();

#pragma unroll
  for (int kt = 0; kt < 5; kt++) {
    const int cur = kt & 1;
    // issue-early prefetch of next K-tile into the other buffer
    if (kt < 4) STAGE_KT(kt + 1, cur ^ 1);

    frag_u af[4], bf[4];
#pragma unroll
    for (int mi = 0; mi < 4; mi++) {
      const int rb_ = (wr * 64 + mi * 16 + m0) * 128;
      af[mi].h[0] = *(const i32x4*)&As[cur][rb_ + cLo];
      af[mi].h[1] = *(const i32x4*)&As[cur][rb_ + cHi];
    }
#pragma unroll
    for (int ni = 0; ni < 4; ni++) {
      const int rb_ = (wc * 64 + ni * 16 + m0) * 128;
      bf[ni].h[0] = *(const i32x4*)&Bs[cur][rb_ + cLo];
      bf[ni].h[1] = *(const i32x4*)&Bs[cur][rb_ + cHi];
    }

    __builtin_amdgcn_s_setprio(1);
#pragma unroll
    for (int mi = 0; mi < 4; mi++)
#pragma unroll
      for (int ni = 0; ni < 4; ni++)
        acc[mi][ni] = __builtin_amdgcn_mfma_scale_f32_16x16x128_f8f6f4(
            af[mi].v, bf[ni].v, acc[mi][ni],
            0 /*cbsz: A=fp8 e4m3*/, 0 /*blgp: B=fp8 e4m3*/,
            0, 0x7F7F7F7Fu /*scale A = 1.0*/,
            0, 0x7F7F7F7Fu /*scale B = 1.0*/);
    __builtin_amdgcn_s_setprio(0);

    if (kt < 4) __syncthreads();
  }
#undef STAGE_KT

  // epilogue: per-row max over this block's 128 columns, then global atomicMax
  const int colBase = bn * BN + wc * 64;
#pragma unroll
  for (int mi = 0; mi < 4; mi++) {
    float rmax[4] = {-3.0e38f, -3.0e38f, -3.0e38f, -3.0e38f};
#pragma unroll
    for (int ni = 0; ni < 4; ni++) {
      bool valid = (colBase + ni * 16 + m0) < N_REAL;
#pragma unroll
      for (int r = 0; r < 4; r++) {
        float v = valid ? acc[mi][ni][r] : -3.0e38f;
        rmax[r] = fmaxf(rmax[r], v);
      }
    }
#pragma unroll
    for (int r = 0; r < 4; r++) {
      float v = rmax[r];
      v = fmaxf(v, __shfl_xor(v, 1));
      v = fmaxf(v, __shfl_xor(v, 2));
      v = fmaxf(v, __shfl_xor(v, 4));
      v = fmaxf(v, __shfl_xor(v, 8));
      rmax[r] = v;
    }
    if (m0 == 0) {
      int row = bm * BM + wr * 64 + mi * 16 + q * 4;
#pragma unroll
      for (int r = 0; r < 4; r++)
        atomicMax(&rowmax[row + r], f2key(rmax[r]));
    }
  }
}

// =====================================================================
// Kernel C: fused tail — ONE kernel, 64 blocks (1 batch row each).
//   favg now computed on the fly: mean over k of fa[k][:] (40 KB, L2).
// =====================================================================
__global__ __launch_bounds__(256) void tail_fused_kernel(
    const unsigned* __restrict__ rowmax, const float* __restrict__ qinv,
    const float* __restrict__ q_img, const float* __restrict__ fa,
    const float* __restrict__ hw1, const float* __restrict__ hb1,
    const float* __restrict__ hg2, const float* __restrict__ hbe2,
    const float* __restrict__ hw2, const float* __restrict__ hb2,
    const float* __restrict__ hg3, const float* __restrict__ hbe3,
    const float* __restrict__ hw3, const float* __restrict__ hb3,
    const float* __restrict__ rw1, const float* __restrict__ rb1,
    const float* __restrict__ rg2, const float* __restrict__ rbe2,
    const float* __restrict__ rw2, const float* __restrict__ rb2,
    const float* __restrict__ rg3, const float* __restrict__ rbe3,
    const float* __restrict__ rw3, const float* __restrict__ rb3,
    float* __restrict__ out) {
  __shared__ float A[240];    // amap row (225)
  __shared__ float R[640];    // res_img row
  __shared__ float P[256];    // GEMV1 partials
  __shared__ float Hr[128];   // ref hidden1 (post bn)
  __shared__ float Hm[128];   // map hidden1 (post bn)
  __shared__ float Q[256];    // layer2 partials (both heads)
  __shared__ float Hr2[64];   // ref hidden2
  __shared__ float Hm2[64];   // map hidden2
  __shared__ float red[16];   // [0..3] amean partials, [8]=s_ref, [9]=s_map

  const int b = blockIdx.x;
  const int tid = threadIdx.x;
  const int wave = tid >> 6, lane = tid & 63;

  // ---- amap row + amean partials; res row (favg on the fly) ----
  float am = 0.f;
  if (tid < P_DIM) {
    float mx = key2f(rowmax[b * P_DIM + tid]);
    float a = 0.5f * (1.f - mx * qinv[b * P_DIM + tid]);
    A[tid] = a;
    am = a;
  }
#pragma unroll
  for (int off = 32; off > 0; off >>= 1) am += __shfl_xor(am, off);
  if (lane == 0) red[wave] = am;
#pragma unroll
  for (int rep = 0; rep < 3; rep++) {
    int i = rep * 256 + tid;
    if (i < D_DIM) {
      float s = 0.f;
#pragma unroll
      for (int k = 0; k < 16; k++) s += fa[k * D_DIM + i];
      R[i] = q_img[b * D_DIM + i] - s * (1.f / 16.f);
    }
  }
  __syncthreads();

  const int j = tid & 127, bh = tid >> 7;

  // ---- s_ref GEMV1: 640 -> 128 (halved over bh) ----
  {
    float acc = bh ? 0.f : rb1[j];
    const int d0 = bh * 320;
#pragma unroll 8
    for (int d = 0; d < 320; d++) acc += R[d0 + d] * rw1[(d0 + d) * 128 + j];
    P[bh * 128 + j] = acc;
  }
  __syncthreads();
  if (tid < 128) Hr[tid] = fmaxf(P[tid] + P[128 + tid], 0.f) * rg2[tid] + rbe2[tid];
  __syncthreads();

  // ---- s_map GEMV1: 225 -> 128 (split 128/97 over bh) ----
  {
    float acc = bh ? 0.f : hb1[j];
    const int p0 = bh * 128;
    const int pn = bh ? (P_DIM - 128) : 128;
#pragma unroll 8
    for (int p = 0; p < pn; p++) acc += A[p0 + p] * hw1[(p0 + p) * 128 + j];
    P[bh * 128 + j] = acc;
  }
  __syncthreads();
  if (tid < 128) Hm[tid] = fmaxf(P[tid] + P[128 + tid], 0.f) * hg2[tid] + hbe2[tid];
  __syncthreads();

  // ---- layer2 both heads: 128 -> 64; g0/g1 = ref halves, g2/g3 = map ----
  {
    const int n = tid & 63, g = tid >> 6;
    const float* h = (g < 2) ? Hr : Hm;
    const float* w = (g < 2) ? rw2 : hw2;
    float acc = (g == 0) ? rb2[n] : (g == 2) ? hb2[n] : 0.f;
    const int j0 = (g & 1) * 64;
#pragma unroll 8
    for (int jj = 0; jj < 64; jj++) acc += h[j0 + jj] * w[(j0 + jj) * 64 + n];
    Q[g * 64 + n] = acc;
  }
  __syncthreads();
  if (tid < 64) Hr2[tid] = fmaxf(Q[tid] + Q[64 + tid], 0.f) * rg3[tid] + rbe3[tid];
  else if (tid < 128) {
    int n = tid - 64;
    Hm2[n] = fmaxf(Q[128 + n] + Q[192 + n], 0.f) * hg3[n] + hbe3[n];
  }
  __syncthreads();

  // ---- layer3 + sigmoid: wave 0 = ref, wave 1 = map ----
  if (wave == 0) {
    float v = Hr2[lane] * rw3[lane];
#pragma unroll
    for (int off = 32; off > 0; off >>= 1) v += __shfl_xor(v, off);
    if (lane == 0) red[8] = sigmoidf(v + rb3[0]);
  } else if (wave == 1) {
    float v = Hm2[lane] * hw3[lane];
#pragma unroll
    for (int off = 32; off > 0; off >>= 1) v += __shfl_xor(v, off);
    if (lane == 0) red[9] = sigmoidf(v + hb3[0]);
  }
  __syncthreads();

  if (tid == 0) {
    float amean = (red[0] + red[1] + red[2] + red[3]) * (1.f / 225.f);
    out[b] = 0.5f * (red[8] + red[9]) + amean;
  }
}

// ---------------- launch ----------------
extern "C" void kernel_launch(void* const* d_in, const int* in_sizes, int n_in,
                              void* d_out, int out_size, void* d_ws, size_t ws_size,
                              hipStream_t stream) {
  const float* q_patch = (const float*)d_in[0];
  const float* r_patch = (const float*)d_in[1];
  const float* q_img   = (const float*)d_in[2];
  const float* r_img   = (const float*)d_in[3];
  const float* adpt_w1 = (const float*)d_in[4];
  const float* adpt_w2 = (const float*)d_in[5];
  const float* dh_w1 = (const float*)d_in[6];
  const float* dh_b1 = (const float*)d_in[7];
  const float* dh_g2 = (const float*)d_in[8];
  const float* dh_be2 = (const float*)d_in[9];
  const float* dh_w2 = (const float*)d_in[10];
  const float* dh_b2 = (const float*)d_in[11];
  const float* dh_g3 = (const float*)d_in[12];
  const float* dh_be3 = (const float*)d_in[13];
  const float* dh_w3 = (const float*)d_in[14];
  const float* dh_b3 = (const float*)d_in[15];
  const float* dr_w1 = (const float*)d_in[16];
  const float* dr_b1 = (const float*)d_in[17];
  const float* dr_g2 = (const float*)d_in[18];
  const float* dr_be2 = (const float*)d_in[19];
  const float* dr_w2 = (const float*)d_in[20];
  const float* dr_b2 = (const float*)d_in[21];
  const float* dr_g3 = (const float*)d_in[22];
  const float* dr_be3 = (const float*)d_in[23];
  const float* dr_w3 = (const float*)d_in[24];
  const float* dr_b3 = (const float*)d_in[25];

  // ws layout (bytes) — fp8 staging buffers
  const size_t QB_BYTES = (size_t)MPAD * D_DIM;   // 9,256,960
  const size_t RB_BYTES = (size_t)NPAD * D_DIM;   // 2,375,680
  char* ws = (char*)d_ws;
  unsigned char* qb = (unsigned char*)(ws);
  unsigned char* rb = (unsigned char*)(ws + QB_BYTES);
  float* qinv        = (float*)(ws + QB_BYTES + RB_BYTES);
  unsigned* rowmax   = (unsigned*)(ws + QB_BYTES + RB_BYTES + (size_t)M_REAL * 4);
  float* fa          = (float*)(ws + QB_BYTES + RB_BYTES + (size_t)M_REAL * 4 + (size_t)MPAD * 4);

  stage_all_kernel<<<ABLKS + QBLKS + RBLKS, 256, 0, stream>>>(
      q_patch, r_patch, r_img, adpt_w1, adpt_w2, qb, rb, qinv, rowmax, fa);
  sim_max_kernel<<<8 * MCHUNK * NTILES, 256, 0, stream>>>(qb, rb, rowmax);
  tail_fused_kernel<<<B_DIM, 256, 0, stream>>>(
      rowmax, qinv, q_img, fa,
      dh_w1, dh_b1, dh_g2, dh_be2, dh_w2, dh_b2, dh_g3, dh_be3, dh_w3, dh_b3,
      dr_w1, dr_b1, dr_g2, dr_be2, dr_w2, dr_b2, dr_g3, dr_be3, dr_w3, dr_b3,
      (float*)d_out);
}